// Round 1
// baseline (3047.959 us; speedup 1.0000x reference)
//
#include <hip/hip_runtime.h>
#include <math.h>

#define BN 32768
#define IND 336
#define HD 256
#define AD 64
#define EN 16
#define TK 4
#define TM 64
#define KC 64
#define STOT (BN * TK)

__device__ __forceinline__ float mishf(float v) {
  float sp = log1pf(expf(v));
  return v * tanhf(sp);
}

// ---------------- init: zero model_out accumulator + scalars ----------------
__global__ void k_init(float* __restrict__ out, int* __restrict__ counts,
                       int* __restrict__ cursor, float* __restrict__ ent) {
  int i = blockIdx.x * 256 + threadIdx.x;
  if (i < BN * AD) out[i] = 0.f;
  if (i < 16) { counts[i] = 0; cursor[i] = 0; }
  if (i == 16) *ent = 0.f;
}

// ---------------- time embedding + input assembly ----------------
__global__ void k_time_inp(const float* __restrict__ x, const float* __restrict__ sigma,
                           const float* __restrict__ state,
                           const float* __restrict__ tW1, const float* __restrict__ tb1,
                           const float* __restrict__ tW2, const float* __restrict__ tb2,
                           float* __restrict__ inp) {
  const int wave = threadIdx.x >> 6;
  const int lane = threadIdx.x & 63;
  const int row = blockIdx.x * 4 + wave;
  const float sg = sigma[row];
  const float rt = 250.0f * logf(sg + 1e-44f);
  // sinusoidal pe: lanes 0..7 sin, 8..15 cos
  float pe = 0.f;
  if (lane < 16) {
    int j = lane & 7;
    float f = expf(-1.3157629102823121f * (float)j);  // -ln(10000)/7 * j
    float ang = rt * f;
    pe = (lane < 8) ? sinf(ang) : cosf(ang);
  }
  // h1 = mish(pe @ tW1 + tb1)  (32 wide, lanes 0..31 hold it)
  float h1;
  {
    float acc = 0.f;
    int j = lane & 31;
    #pragma unroll
    for (int i = 0; i < 16; ++i) {
      float p = __shfl(pe, i, 64);
      acc = fmaf(p, tW1[i * 32 + j], acc);
    }
    acc += tb1[j];
    h1 = mishf(acc);
  }
  // t = h1 @ tW2 + tb2 (16 wide)
  float t2;
  {
    float acc = 0.f;
    int j = lane & 15;
    #pragma unroll
    for (int i = 0; i < 32; ++i) {
      float h = __shfl(h1, i, 64);
      acc = fmaf(h, tW2[i * 16 + j], acc);
    }
    t2 = acc + tb2[j];
  }
  const float c_in = rsqrtf(sg * sg + 0.25f);
  float* orow = inp + (size_t)row * IND;
  orow[lane] = c_in * x[row * 64 + lane];
  if (lane < 16) orow[64 + lane] = t2;
  #pragma unroll
  for (int r = 0; r < 4; ++r)
    orow[80 + r * 64 + lane] = state[row * 256 + r * 64 + lane];
}

// ---------------- gate: GEMM + relu + 256->16 + softmax + top4 ----------------
__global__ __launch_bounds__(256, 1) void k_gate(
    const float* __restrict__ inp, const float* __restrict__ gW1,
    const float* __restrict__ gb1, const float* __restrict__ gW2,
    const float* __restrict__ gb2, int* __restrict__ topk_idx,
    float* __restrict__ topk_w, int* __restrict__ counts,
    float* __restrict__ ent_sum) {
  __shared__ float sA[TM * 65];
  __shared__ float sB[KC * 256];
  __shared__ float sH[TM * 257];
  __shared__ int scnt[16];
  const int tid = threadIdx.x;
  const int tx = tid & 31, ty = tid >> 5;
  const int row0 = blockIdx.x * TM;
  if (tid < 16) scnt[tid] = 0;

  float acc[8][8];
  #pragma unroll
  for (int i = 0; i < 8; ++i)
    #pragma unroll
    for (int j = 0; j < 8; ++j) acc[i][j] = 0.f;

  for (int k0 = 0; k0 < IND; k0 += KC) {
    #pragma unroll
    for (int it = 0; it < 4; ++it) {
      int idx = tid + it * 256;
      int m = idx >> 4, f4 = idx & 15;
      int kk = k0 + f4 * 4;
      float4 v = make_float4(0.f, 0.f, 0.f, 0.f);
      if (kk < IND) v = *(const float4*)(inp + (size_t)(row0 + m) * IND + kk);
      float* d = &sA[m * 65 + f4 * 4];
      d[0] = v.x; d[1] = v.y; d[2] = v.z; d[3] = v.w;
    }
    #pragma unroll
    for (int it = 0; it < 16; ++it) {
      int idx = tid + it * 256;
      int kr = idx >> 6, cc = idx & 63;
      float4 v = make_float4(0.f, 0.f, 0.f, 0.f);
      if (k0 + kr < IND) v = *(const float4*)(gW1 + (size_t)(k0 + kr) * 256 + cc * 4);
      *(float4*)&sB[kr * 256 + cc * 4] = v;
    }
    __syncthreads();
    const int kmax = min(KC, IND - k0);
    #pragma unroll 4
    for (int kk = 0; kk < kmax; ++kk) {
      float a[8];
      #pragma unroll
      for (int i = 0; i < 8; ++i) a[i] = sA[(ty * 8 + i) * 65 + kk];
      #pragma unroll
      for (int j = 0; j < 8; ++j) {
        float b = sB[kk * 256 + tx + j * 32];
        #pragma unroll
        for (int i = 0; i < 8; ++i) acc[i][j] = fmaf(a[i], b, acc[i][j]);
      }
    }
    __syncthreads();
  }
  #pragma unroll
  for (int i = 0; i < 8; ++i) {
    int r = ty * 8 + i;
    #pragma unroll
    for (int j = 0; j < 8; ++j) {
      int c = tx + j * 32;
      sH[r * 257 + c] = fmaxf(acc[i][j] + gb1[c], 0.f);
    }
  }
  // stage gW2 (256x16)
  #pragma unroll
  for (int it = 0; it < 4; ++it) {
    int idx = tid + it * 256;
    *(float4*)&sB[idx * 4] = *(const float4*)(gW2 + (size_t)idx * 4);
  }
  __syncthreads();
  {
    const int r = tid >> 2, q = tid & 3;
    float g0 = 0.f, g1 = 0.f, g2 = 0.f, g3 = 0.f;
    for (int k = 0; k < 256; ++k) {
      float a = sH[r * 257 + k];
      float4 bv = *(const float4*)&sB[k * 16 + q * 4];
      g0 = fmaf(a, bv.x, g0); g1 = fmaf(a, bv.y, g1);
      g2 = fmaf(a, bv.z, g2); g3 = fmaf(a, bv.w, g3);
    }
    sA[r * 16 + q * 4 + 0] = g0 + gb2[q * 4 + 0];
    sA[r * 16 + q * 4 + 1] = g1 + gb2[q * 4 + 1];
    sA[r * 16 + q * 4 + 2] = g2 + gb2[q * 4 + 2];
    sA[r * 16 + q * 4 + 3] = g3 + gb2[q * 4 + 3];
  }
  __syncthreads();
  float entc = 0.f;
  if (tid < 64) {
    const int row = row0 + tid;
    float g[16], mx = -1e30f;
    #pragma unroll
    for (int e = 0; e < 16; ++e) { g[e] = sA[tid * 16 + e]; mx = fmaxf(mx, g[e]); }
    float p[16], s = 0.f;
    #pragma unroll
    for (int e = 0; e < 16; ++e) { p[e] = expf(g[e] - mx); s += p[e]; }
    const float inv = 1.f / s;
    #pragma unroll
    for (int e = 0; e < 16; ++e) {
      float pr = p[e] * inv;
      entc -= pr * logf(pr + 1e-9f);
    }
    // top-4, strict > keeps lowest index on ties (jax.lax.top_k semantics)
    int idxs[4]; float scs[4];
    unsigned used = 0;
    float wsum = 1e-9f;
    #pragma unroll
    for (int k = 0; k < 4; ++k) {
      int be = 0; float bv = -1.f;
      #pragma unroll
      for (int e = 0; e < 16; ++e) {
        float pr = p[e] * inv;
        if (!((used >> e) & 1u) && pr > bv) { bv = pr; be = e; }
      }
      used |= (1u << be);
      idxs[k] = be; scs[k] = bv;
      wsum += bv;
    }
    #pragma unroll
    for (int k = 0; k < 4; ++k) {
      topk_idx[row * 4 + k] = idxs[k];
      topk_w[row * 4 + k] = scs[k] / wsum;
      atomicAdd(&scnt[idxs[k]], 1);
    }
    #pragma unroll
    for (int off = 32; off > 0; off >>= 1) entc += __shfl_down(entc, off, 64);
  }
  __syncthreads();
  if (tid == 0) atomicAdd(ent_sum, entc);
  if (tid < 16 && scnt[tid] > 0) atomicAdd(&counts[tid], scnt[tid]);
}

// ---------------- offsets + tile-block starts + aux loss ----------------
__global__ void k_aux(const int* __restrict__ counts, const float* __restrict__ ent_sum,
                      int* __restrict__ offsets, int* __restrict__ tbk,
                      float* __restrict__ aux_out) {
  if (threadIdx.x == 0) {
    int off = 0, t = 0;
    float load[16], mean = 0.f;
    for (int e = 0; e < 16; ++e) {
      offsets[e] = off; tbk[e] = t;
      int c = counts[e];
      off += c;
      t += (c + TM - 1) / TM;
      load[e] = (float)c / (32768.0f + 1e-9f);
      mean += load[e];
    }
    offsets[16] = off; tbk[16] = t;
    mean *= (1.f / 16.f);
    float var = 0.f;
    for (int e = 0; e < 16; ++e) { float d = load[e] - mean; var += d * d; }
    var *= (1.f / 15.f);
    *aux_out = var + ent_sum[0] * (1.0f / 32768.0f);
  }
}

// ---------------- scatter slots grouped by expert ----------------
__global__ void k_scatter(const int* __restrict__ topk_idx, const float* __restrict__ topk_w,
                          const int* __restrict__ offsets, int* __restrict__ cursor,
                          int* __restrict__ slot_row, float* __restrict__ slot_w) {
  int row = blockIdx.x * 256 + threadIdx.x;
  if (row >= BN) return;
  #pragma unroll
  for (int k = 0; k < 4; ++k) {
    int e = topk_idx[row * 4 + k];
    float w = topk_w[row * 4 + k];
    int pos = atomicAdd(&cursor[e], 1);
    int s = offsets[e] + pos;
    slot_row[s] = row;
    slot_w[s] = w;
  }
}

// ---------------- fused expert (3 layers + fW) per 64-slot tile ----------------
__device__ __forceinline__ void layer256(const float* __restrict__ W,
                                         const float* __restrict__ bias,
                                         float* sH, float* sB,
                                         int tid, int tx, int ty) {
  float acc[8][8];
  #pragma unroll
  for (int i = 0; i < 8; ++i)
    #pragma unroll
    for (int j = 0; j < 8; ++j) acc[i][j] = 0.f;
  for (int k0 = 0; k0 < HD; k0 += KC) {
    #pragma unroll
    for (int it = 0; it < 16; ++it) {
      int idx = tid + it * 256;
      int kr = idx >> 6, cc = idx & 63;
      *(float4*)&sB[kr * 256 + cc * 4] = *(const float4*)(W + (size_t)(k0 + kr) * 256 + cc * 4);
    }
    __syncthreads();
    #pragma unroll 4
    for (int kk = 0; kk < KC; ++kk) {
      float a[8];
      #pragma unroll
      for (int i = 0; i < 8; ++i) a[i] = sH[(ty * 8 + i) * 257 + k0 + kk];
      #pragma unroll
      for (int j = 0; j < 8; ++j) {
        float b = sB[kk * 256 + tx + j * 32];
        #pragma unroll
        for (int i = 0; i < 8; ++i) acc[i][j] = fmaf(a[i], b, acc[i][j]);
      }
    }
    __syncthreads();
  }
  #pragma unroll
  for (int i = 0; i < 8; ++i) {
    int r = ty * 8 + i;
    #pragma unroll
    for (int j = 0; j < 8; ++j) {
      int c = tx + j * 32;
      sH[r * 257 + c] = mishf(acc[i][j] + bias[c]);
    }
  }
  __syncthreads();
}

__global__ __launch_bounds__(256, 1) void k_expert(
    const float* __restrict__ inp, const float* __restrict__ eW1,
    const float* __restrict__ eb1, const float* __restrict__ eW2,
    const float* __restrict__ eb2, const float* __restrict__ eW3,
    const float* __restrict__ eb3, const float* __restrict__ fW,
    const int* __restrict__ offsets, const int* __restrict__ counts,
    const int* __restrict__ tbk, const int* __restrict__ slot_row,
    const float* __restrict__ slot_w, float* __restrict__ out) {
  __shared__ float sA[TM * 65];
  __shared__ float sB[KC * 256];
  __shared__ float sH[TM * 257];
  __shared__ int sRows[TM];
  __shared__ float sW[TM];

  const int bid = blockIdx.x;
  if (bid >= tbk[16]) return;
  int e = 0;
  #pragma unroll
  for (int i = 1; i < 16; ++i)
    if (bid >= tbk[i]) e = i;
  const int tile = bid - tbk[e];
  const int cnt = counts[e];
  const int s0 = offsets[e] + tile * TM;
  const int nr = min(TM, cnt - tile * TM);
  const int tid = threadIdx.x;
  const int tx = tid & 31, ty = tid >> 5;

  if (tid < TM) {
    sRows[tid] = (tid < nr) ? slot_row[s0 + tid] : 0;
    sW[tid] = (tid < nr) ? slot_w[s0 + tid] : 0.f;
  }
  __syncthreads();

  float acc[8][8];
  #pragma unroll
  for (int i = 0; i < 8; ++i)
    #pragma unroll
    for (int j = 0; j < 8; ++j) acc[i][j] = 0.f;

  const float* W1 = eW1 + (size_t)e * IND * HD;
  for (int k0 = 0; k0 < IND; k0 += KC) {
    #pragma unroll
    for (int it = 0; it < 4; ++it) {
      int idx = tid + it * 256;
      int m = idx >> 4, f4 = idx & 15;
      int kk = k0 + f4 * 4;
      float4 v = make_float4(0.f, 0.f, 0.f, 0.f);
      if (kk < IND) v = *(const float4*)(inp + (size_t)sRows[m] * IND + kk);
      float* d = &sA[m * 65 + f4 * 4];
      d[0] = v.x; d[1] = v.y; d[2] = v.z; d[3] = v.w;
    }
    #pragma unroll
    for (int it = 0; it < 16; ++it) {
      int idx = tid + it * 256;
      int kr = idx >> 6, cc = idx & 63;
      float4 v = make_float4(0.f, 0.f, 0.f, 0.f);
      if (k0 + kr < IND) v = *(const float4*)(W1 + (size_t)(k0 + kr) * 256 + cc * 4);
      *(float4*)&sB[kr * 256 + cc * 4] = v;
    }
    __syncthreads();
    const int kmax = min(KC, IND - k0);
    #pragma unroll 4
    for (int kk = 0; kk < kmax; ++kk) {
      float a[8];
      #pragma unroll
      for (int i = 0; i < 8; ++i) a[i] = sA[(ty * 8 + i) * 65 + kk];
      #pragma unroll
      for (int j = 0; j < 8; ++j) {
        float b = sB[kk * 256 + tx + j * 32];
        #pragma unroll
        for (int i = 0; i < 8; ++i) acc[i][j] = fmaf(a[i], b, acc[i][j]);
      }
    }
    __syncthreads();
  }
  const float* b1 = eb1 + e * HD;
  #pragma unroll
  for (int i = 0; i < 8; ++i) {
    int r = ty * 8 + i;
    #pragma unroll
    for (int j = 0; j < 8; ++j) {
      int c = tx + j * 32;
      sH[r * 257 + c] = mishf(acc[i][j] + b1[c]);
    }
  }
  __syncthreads();

  layer256(eW2 + (size_t)e * HD * HD, eb2 + e * HD, sH, sB, tid, tx, ty);
  layer256(eW3 + (size_t)e * HD * HD, eb3 + e * HD, sH, sB, tid, tx, ty);

  // final projection: stage full fW (256x64 = 64KB) then accumulate
  #pragma unroll
  for (int it = 0; it < 16; ++it) {
    int idx = tid + it * 256;
    *(float4*)&sB[idx * 4] = *(const float4*)(fW + (size_t)idx * 4);
  }
  __syncthreads();
  float acc2[8][2];
  #pragma unroll
  for (int i = 0; i < 8; ++i) { acc2[i][0] = 0.f; acc2[i][1] = 0.f; }
  #pragma unroll 4
  for (int k = 0; k < 256; ++k) {
    float a[8];
    #pragma unroll
    for (int i = 0; i < 8; ++i) a[i] = sH[(ty * 8 + i) * 257 + k];
    float b0 = sB[k * 64 + tx];
    float b1v = sB[k * 64 + tx + 32];
    #pragma unroll
    for (int i = 0; i < 8; ++i) {
      acc2[i][0] = fmaf(a[i], b0, acc2[i][0]);
      acc2[i][1] = fmaf(a[i], b1v, acc2[i][1]);
    }
  }
  #pragma unroll
  for (int i = 0; i < 8; ++i) {
    int m = ty * 8 + i;
    if (m < nr) {
      int row = sRows[m];
      float wv = sW[m];
      atomicAdd(&out[(size_t)row * AD + tx], wv * acc2[i][0]);
      atomicAdd(&out[(size_t)row * AD + tx + 32], wv * acc2[i][1]);
    }
  }
}

// ---------------- epilogue: consistency scalings + clip ----------------
__global__ void k_final(const float* __restrict__ x, const float* __restrict__ sigma,
                        const float* __restrict__ fb, float* __restrict__ out) {
  int i = blockIdx.x * 256 + threadIdx.x;
  if (i >= BN * AD) return;
  int row = i >> 6, c = i & 63;
  float sg = sigma[row];
  float sm = sg - 0.002f;
  float c_skip = 0.25f / (sm * sm + 0.25f);
  float c_out = sm * 0.5f * rsqrtf(sg * sg + 0.25f);
  float d = c_out * (out[i] + fb[c]) + c_skip * x[i];
  out[i] = fminf(fmaxf(d, -1.f), 1.f);
}

extern "C" void kernel_launch(void* const* d_in, const int* in_sizes, int n_in,
                              void* d_out, int out_size, void* d_ws, size_t ws_size,
                              hipStream_t stream) {
  const float* x     = (const float*)d_in[0];
  const float* sigma = (const float*)d_in[1];
  const float* state = (const float*)d_in[2];
  const float* tW1   = (const float*)d_in[3];
  const float* tb1   = (const float*)d_in[4];
  const float* tW2   = (const float*)d_in[5];
  const float* tb2   = (const float*)d_in[6];
  const float* gW1   = (const float*)d_in[7];
  const float* gb1   = (const float*)d_in[8];
  const float* gW2   = (const float*)d_in[9];
  const float* gb2   = (const float*)d_in[10];
  const float* eW1   = (const float*)d_in[11];
  const float* eb1   = (const float*)d_in[12];
  const float* eW2   = (const float*)d_in[13];
  const float* eb2   = (const float*)d_in[14];
  const float* eW3   = (const float*)d_in[15];
  const float* eb3   = (const float*)d_in[16];
  const float* fW    = (const float*)d_in[17];
  const float* fb    = (const float*)d_in[18];
  float* out = (float*)d_out;

  char* w = (char*)d_ws;
  float* inp      = (float*)w; w += (size_t)BN * IND * 4;
  int*   topk_idx = (int*)w;   w += (size_t)BN * 4 * 4;
  float* topk_w   = (float*)w; w += (size_t)BN * 4 * 4;
  int*   counts   = (int*)w;   w += 16 * 4;
  int*   cursor   = (int*)w;   w += 16 * 4;
  int*   offsets  = (int*)w;   w += 17 * 4;
  int*   tbk      = (int*)w;   w += 17 * 4;
  float* ent      = (float*)w; w += 4;
  int*   slot_row = (int*)w;   w += (size_t)STOT * 4;
  float* slot_w   = (float*)w; w += (size_t)STOT * 4;

  k_init<<<(BN * AD + 255) / 256, 256, 0, stream>>>(out, counts, cursor, ent);
  k_time_inp<<<BN / 4, 256, 0, stream>>>(x, sigma, state, tW1, tb1, tW2, tb2, inp);
  k_gate<<<BN / TM, 256, 0, stream>>>(inp, gW1, gb1, gW2, gb2, topk_idx, topk_w, counts, ent);
  k_aux<<<1, 64, 0, stream>>>(counts, ent, offsets, tbk, out + (size_t)BN * AD);
  k_scatter<<<BN / 256, 256, 0, stream>>>(topk_idx, topk_w, offsets, cursor, slot_row, slot_w);
  k_expert<<<STOT / TM + EN, 256, 0, stream>>>(inp, eW1, eb1, eW2, eb2, eW3, eb3, fW,
                                               offsets, counts, tbk, slot_row, slot_w, out);
  k_final<<<(BN * AD + 255) / 256, 256, 0, stream>>>(x, sigma, fb, out);
}

// Round 3
// 533.099 us; speedup vs baseline: 5.7174x; 5.7174x over previous
//
#include <hip/hip_runtime.h>
#include <math.h>

#define BN 32768
#define INDP 352      // padded input width (336 -> 352, zero-filled)
#define HD 256
#define AD 64
#define EN 16
#define TM 64
#define STOT (BN * 4)

typedef __attribute__((ext_vector_type(8))) short s8v;
typedef __attribute__((ext_vector_type(4))) float f4v;
typedef unsigned short u16;

__device__ __forceinline__ u16 f2bf(float x) {
  unsigned u = __float_as_uint(x);
  return (u16)((u + 0x7fffu + ((u >> 16) & 1u)) >> 16);
}
__device__ __forceinline__ float bf2f(u16 h) { return __uint_as_float(((unsigned)h) << 16); }
__device__ __forceinline__ float rcpf(float a) { float r; asm("v_rcp_f32 %0, %1" : "=v"(r) : "v"(a)); return r; }
// mish(x) = x*tanh(softplus(x)) = x*(u^2+2u)/(u^2+2u+2), u=e^x (exact algebraic rewrite)
__device__ __forceinline__ float mishf(float x) {
  float xc = fminf(x, 30.f);
  float u = __expf(xc);
  float w = fmaf(u, u, u + u);
  return x * w * rcpf(w + 2.f);
}
__device__ __forceinline__ f4v mfma16(s8v a, s8v b, f4v c) {
  return __builtin_amdgcn_mfma_f32_16x16x32_bf16(a, b, c, 0, 0, 0);
}
__device__ __forceinline__ void pack8(const u16* q, u16* d) {
  uint4 u;
  u.x = q[0] | ((unsigned)q[1] << 16); u.y = q[2] | ((unsigned)q[3] << 16);
  u.z = q[4] | ((unsigned)q[5] << 16); u.w = q[6] | ((unsigned)q[7] << 16);
  *(uint4*)d = u;
}

// ---------------- init ----------------
__global__ void k_init(float* __restrict__ out, int* __restrict__ counts,
                       int* __restrict__ cursor, float* __restrict__ ent) {
  int i = blockIdx.x * 256 + threadIdx.x;
  if (i < BN * AD) out[i] = 0.f;
  if (i < 16) { counts[i] = 0; cursor[i] = 0; }
  if (i == 16) *ent = 0.f;
}

// ------- weight prep: fp32 [K][N] -> fragment-ordered split-bf16 planes -------
// dst (u16 units): [s][nt][plane 0..NP-1][lane 0..63][8]; elem i of lane l:
//   k = s*32 + 8*(l>>4) + i, n = nt*16 + (l&15)
__global__ void k_prep(const float* __restrict__ src, u16* __restrict__ dst,
                       int Ksrc, int Spad, int NT, int N,
                       long sStride, long dStride, int NP, int total) {
  int idx = blockIdx.x * 256 + threadIdx.x;
  if (idx >= total) return;
  int l = idx & 63;
  int t = idx >> 6;
  int nt = t % NT; t /= NT;
  int s = t % Spad; t /= Spad;
  int m = t;
  const float* sp = src + (size_t)m * sStride;
  int n = nt * 16 + (l & 15);
  int kb = s * 32 + (l >> 4) * 8;
  u16 q0[8], q1[8], q2[8];
  #pragma unroll
  for (int i = 0; i < 8; ++i) {
    int k = kb + i;
    float v = (k < Ksrc) ? sp[(size_t)k * N + n] : 0.f;
    u16 a = f2bf(v); float r1 = v - bf2f(a);
    u16 b = f2bf(r1); float r2 = r1 - bf2f(b);
    q0[i] = a; q1[i] = b; q2[i] = f2bf(r2);
  }
  u16* d = dst + (size_t)m * dStride + (size_t)((s * NT + nt) * NP) * 512 + l * 8;
  pack8(q0, d);
  pack8(q1, d + 512);
  if (NP == 3) pack8(q2, d + 1024);
}

// ------- time embedding + input assembly (3 split-bf16 planes) -------
__global__ void k_time_inp(const float* __restrict__ x, const float* __restrict__ sigma,
                           const float* __restrict__ state,
                           const float* __restrict__ tW1, const float* __restrict__ tb1,
                           const float* __restrict__ tW2, const float* __restrict__ tb2,
                           u16* __restrict__ p0, u16* __restrict__ p1, u16* __restrict__ p2) {
  const int wv = threadIdx.x >> 6;
  const int lane = threadIdx.x & 63;
  const int row = blockIdx.x * 4 + wv;
  const float sg = sigma[row];
  const float rt = 250.0f * logf(sg + 1e-44f);
  float pe = 0.f;
  if (lane < 16) {
    int j = lane & 7;
    float f = expf(-1.3157629102823121f * (float)j);  // -ln(10000)/7 * j
    float ang = rt * f;
    pe = (lane < 8) ? sinf(ang) : cosf(ang);
  }
  float h1;
  {
    float acc = 0.f;
    int j = lane & 31;
    #pragma unroll
    for (int i = 0; i < 16; ++i) {
      float p = __shfl(pe, i, 64);
      acc = fmaf(p, tW1[i * 32 + j], acc);
    }
    acc += tb1[j];
    float sp = log1pf(expf(acc));
    h1 = acc * tanhf(sp);
  }
  float t2;
  {
    float acc = 0.f;
    int j = lane & 15;
    #pragma unroll
    for (int i = 0; i < 32; ++i) {
      float h = __shfl(h1, i, 64);
      acc = fmaf(h, tW2[i * 16 + j], acc);
    }
    t2 = acc + tb2[j];
  }
  const float c_in = rsqrtf(sg * sg + 0.25f);
  u16* r0 = p0 + (size_t)row * INDP;
  u16* r1 = p1 + (size_t)row * INDP;
  u16* r2 = p2 + (size_t)row * INDP;
  auto wsplit = [&](int c, float v) {
    u16 a = f2bf(v); float ra = v - bf2f(a);
    u16 b = f2bf(ra); float rb = ra - bf2f(b);
    r0[c] = a; r1[c] = b; r2[c] = f2bf(rb);
  };
  wsplit(lane, c_in * x[row * 64 + lane]);
  if (lane < 16) wsplit(64 + lane, t2);
  #pragma unroll
  for (int r = 0; r < 4; ++r)
    wsplit(80 + r * 64 + lane, state[(size_t)row * 256 + r * 64 + lane]);
  if (lane < 16) { r0[336 + lane] = 0; r1[336 + lane] = 0; r2[336 + lane] = 0; }
}

// ------- gate: 6-term split MFMA layer1 (fp32-grade) + relu + 256->16 + softmax + top4 -------
__global__ __launch_bounds__(256) void k_gate(
    const u16* __restrict__ p0, const u16* __restrict__ p1, const u16* __restrict__ p2,
    const u16* __restrict__ gW1b, const float* __restrict__ gb1,
    const float* __restrict__ gW2, const float* __restrict__ gb2,
    int* __restrict__ topk_idx, float* __restrict__ topk_w,
    int* __restrict__ counts, float* __restrict__ ent_sum) {
  __shared__ float sH[TM * 257];
  __shared__ float sB2[256 * 16];
  __shared__ float sLog[TM * 16];
  __shared__ int scnt[16];
  const int tid = threadIdx.x;
  const int l = tid & 63, w = tid >> 6;
  const int g = l >> 4, r16 = l & 15;
  const int row0 = blockIdx.x * TM;
  if (tid < 16) scnt[tid] = 0;

  f4v acc[4][4];
  #pragma unroll
  for (int i = 0; i < 4; ++i)
    #pragma unroll
    for (int j = 0; j < 4; ++j) acc[i][j] = (f4v){0.f, 0.f, 0.f, 0.f};

  for (int s = 0; s < 11; ++s) {
    s8v a0[4], a1[4], a2[4], b0[4], b1[4], b2[4];
    #pragma unroll
    for (int mt = 0; mt < 4; ++mt) {
      size_t off = (size_t)(row0 + mt * 16 + r16) * INDP + s * 32 + g * 8;
      a0[mt] = *(const s8v*)(p0 + off);
      a1[mt] = *(const s8v*)(p1 + off);
      a2[mt] = *(const s8v*)(p2 + off);
    }
    #pragma unroll
    for (int j = 0; j < 4; ++j) {
      const u16* pb = gW1b + (size_t)((s * 16 + w * 4 + j) * 3) * 512 + l * 8;
      b0[j] = *(const s8v*)pb;
      b1[j] = *(const s8v*)(pb + 512);
      b2[j] = *(const s8v*)(pb + 1024);
    }
    #pragma unroll
    for (int mt = 0; mt < 4; ++mt)
      #pragma unroll
      for (int j = 0; j < 4; ++j) {
        acc[mt][j] = mfma16(a0[mt], b0[j], acc[mt][j]);
        acc[mt][j] = mfma16(a0[mt], b1[j], acc[mt][j]);
        acc[mt][j] = mfma16(a1[mt], b0[j], acc[mt][j]);
        acc[mt][j] = mfma16(a1[mt], b1[j], acc[mt][j]);
        acc[mt][j] = mfma16(a0[mt], b2[j], acc[mt][j]);
        acc[mt][j] = mfma16(a2[mt], b0[j], acc[mt][j]);
      }
  }
  float bj[4];
  #pragma unroll
  for (int j = 0; j < 4; ++j) bj[j] = gb1[w * 64 + j * 16 + r16];
  #pragma unroll
  for (int mt = 0; mt < 4; ++mt)
    #pragma unroll
    for (int j = 0; j < 4; ++j)
      #pragma unroll
      for (int r = 0; r < 4; ++r) {
        int row = mt * 16 + g * 4 + r;
        sH[row * 257 + w * 64 + j * 16 + r16] = fmaxf(acc[mt][j][r] + bj[j], 0.f);
      }
  #pragma unroll
  for (int it = 0; it < 4; ++it) {
    int idx = tid + it * 256;
    *(float4*)&sB2[idx * 4] = *(const float4*)(gW2 + (size_t)idx * 4);
  }
  __syncthreads();
  {
    const int rr = tid >> 2, q = tid & 3;
    float g0 = 0.f, g1 = 0.f, g2 = 0.f, g3 = 0.f;
    for (int k = 0; k < 256; ++k) {
      float a = sH[rr * 257 + k];
      float4 bv = *(const float4*)&sB2[k * 16 + q * 4];
      g0 = fmaf(a, bv.x, g0); g1 = fmaf(a, bv.y, g1);
      g2 = fmaf(a, bv.z, g2); g3 = fmaf(a, bv.w, g3);
    }
    sLog[rr * 16 + q * 4 + 0] = g0 + gb2[q * 4 + 0];
    sLog[rr * 16 + q * 4 + 1] = g1 + gb2[q * 4 + 1];
    sLog[rr * 16 + q * 4 + 2] = g2 + gb2[q * 4 + 2];
    sLog[rr * 16 + q * 4 + 3] = g3 + gb2[q * 4 + 3];
  }
  __syncthreads();
  float entc = 0.f;
  if (tid < 64) {
    const int row = row0 + tid;
    float gx[16], mx = -1e30f;
    #pragma unroll
    for (int e = 0; e < 16; ++e) { gx[e] = sLog[tid * 16 + e]; mx = fmaxf(mx, gx[e]); }
    float p[16], s = 0.f;
    #pragma unroll
    for (int e = 0; e < 16; ++e) { p[e] = expf(gx[e] - mx); s += p[e]; }
    const float inv = 1.f / s;
    #pragma unroll
    for (int e = 0; e < 16; ++e) {
      float pr = p[e] * inv;
      entc -= pr * logf(pr + 1e-9f);
    }
    int idxs[4]; float scs[4];
    unsigned used = 0;
    float wsum = 1e-9f;
    #pragma unroll
    for (int k = 0; k < 4; ++k) {
      int be = 0; float bv = -1.f;
      #pragma unroll
      for (int e = 0; e < 16; ++e) {
        float pr = p[e] * inv;
        if (!((used >> e) & 1u) && pr > bv) { bv = pr; be = e; }
      }
      used |= (1u << be);
      idxs[k] = be; scs[k] = bv;
      wsum += bv;
    }
    #pragma unroll
    for (int k = 0; k < 4; ++k) {
      topk_idx[row * 4 + k] = idxs[k];
      topk_w[row * 4 + k] = scs[k] / wsum;
      atomicAdd(&scnt[idxs[k]], 1);
    }
    #pragma unroll
    for (int off = 32; off > 0; off >>= 1) entc += __shfl_down(entc, off, 64);
  }
  __syncthreads();
  if (tid == 0) atomicAdd(ent_sum, entc);
  if (tid < 16 && scnt[tid] > 0) atomicAdd(&counts[tid], scnt[tid]);
}

// ---------------- offsets + aux loss ----------------
__global__ void k_aux(const int* __restrict__ counts, const float* __restrict__ ent_sum,
                      int* __restrict__ offsets, int* __restrict__ tbk,
                      float* __restrict__ aux_out) {
  if (threadIdx.x == 0) {
    int off = 0, t = 0;
    float load[16], mean = 0.f;
    for (int e = 0; e < 16; ++e) {
      offsets[e] = off; tbk[e] = t;
      int c = counts[e];
      off += c;
      t += (c + TM - 1) / TM;
      load[e] = (float)c / (32768.0f + 1e-9f);
      mean += load[e];
    }
    offsets[16] = off; tbk[16] = t;
    mean *= (1.f / 16.f);
    float var = 0.f;
    for (int e = 0; e < 16; ++e) { float d = load[e] - mean; var += d * d; }
    var *= (1.f / 15.f);
    *aux_out = var + ent_sum[0] * (1.0f / 32768.0f);
  }
}

// ------- scatter: block-aggregated (16 global atomics per block) -------
__global__ void k_scatter(const int* __restrict__ topk_idx, const float* __restrict__ topk_w,
                          const int* __restrict__ offsets, int* __restrict__ cursor,
                          int* __restrict__ slot_row, float* __restrict__ slot_w) {
  __shared__ int cnt[16];
  __shared__ int base[16];
  const int tid = threadIdx.x;
  if (tid < 16) cnt[tid] = 0;
  __syncthreads();
  const int row = blockIdx.x * 256 + tid;
  int e4[4]; float w4[4]; int lp[4];
  #pragma unroll
  for (int k = 0; k < 4; ++k) {
    e4[k] = topk_idx[row * 4 + k];
    w4[k] = topk_w[row * 4 + k];
    lp[k] = atomicAdd(&cnt[e4[k]], 1);
  }
  __syncthreads();
  if (tid < 16) base[tid] = atomicAdd(&cursor[tid], cnt[tid]);
  __syncthreads();
  #pragma unroll
  for (int k = 0; k < 4; ++k) {
    int s = offsets[e4[k]] + base[e4[k]] + lp[k];
    slot_row[s] = row;
    slot_w[s] = w4[k];
  }
}

// ------- fused expert: 3 MFMA layers + fW, 3-term split-bf16 -------
__global__ __launch_bounds__(256, 2) void k_expert(
    const u16* __restrict__ inpHi, const u16* __restrict__ inpLo,
    const u16* __restrict__ eW1b, const float* __restrict__ eb1,
    const u16* __restrict__ eW2b, const float* __restrict__ eb2,
    const u16* __restrict__ eW3b, const float* __restrict__ eb3,
    const u16* __restrict__ fWb,
    const int* __restrict__ offsets, const int* __restrict__ counts,
    const int* __restrict__ tbk, const int* __restrict__ slot_row,
    const float* __restrict__ slot_w, float* __restrict__ out) {
  __shared__ __align__(16) u16 sHi[TM * 256];
  __shared__ __align__(16) u16 sLo[TM * 256];
  __shared__ int sRows[TM];
  __shared__ float sWv[TM];

  const int bid = blockIdx.x;
  if (bid >= tbk[16]) return;
  int e = 0;
  #pragma unroll
  for (int i = 1; i < 16; ++i)
    if (bid >= tbk[i]) e = i;
  const int tile = bid - tbk[e];
  const int cnt = counts[e];
  const int s0 = offsets[e] + tile * TM;
  const int nr = min(TM, cnt - tile * TM);
  const int tid = threadIdx.x;
  const int l = tid & 63, w = tid >> 6;
  const int g = l >> 4, r16 = l & 15;
  const int swz = (r16 & 7) << 3;  // element-level XOR swizzle (16B granules)

  if (tid < TM) {
    sRows[tid] = (tid < nr) ? slot_row[s0 + tid] : slot_row[s0];
    sWv[tid] = (tid < nr) ? slot_w[s0 + tid] : 0.f;
  }
  __syncthreads();

  size_t rbase[4];
  #pragma unroll
  for (int mt = 0; mt < 4; ++mt) rbase[mt] = (size_t)sRows[mt * 16 + r16] * INDP;

  f4v acc[4][4];
  #pragma unroll
  for (int i = 0; i < 4; ++i)
    #pragma unroll
    for (int j = 0; j < 4; ++j) acc[i][j] = (f4v){0.f, 0.f, 0.f, 0.f};

  // ---- layer 1: K=352, A direct from global planes ----
  const u16* W1 = eW1b + (size_t)e * 180224;
  for (int s = 0; s < 11; ++s) {
    s8v ah[4], al[4], bh[4], bl[4];
    #pragma unroll
    for (int mt = 0; mt < 4; ++mt) {
      size_t off = rbase[mt] + s * 32 + g * 8;
      ah[mt] = *(const s8v*)(inpHi + off);
      al[mt] = *(const s8v*)(inpLo + off);
    }
    #pragma unroll
    for (int j = 0; j < 4; ++j) {
      const u16* pb = W1 + (size_t)((s * 16 + w * 4 + j) * 2) * 512 + l * 8;
      bh[j] = *(const s8v*)pb;
      bl[j] = *(const s8v*)(pb + 512);
    }
    #pragma unroll
    for (int mt = 0; mt < 4; ++mt)
      #pragma unroll
      for (int j = 0; j < 4; ++j) {
        acc[mt][j] = mfma16(ah[mt], bh[j], acc[mt][j]);
        acc[mt][j] = mfma16(al[mt], bh[j], acc[mt][j]);
        acc[mt][j] = mfma16(ah[mt], bl[j], acc[mt][j]);
      }
  }
  {
    const float* b1 = eb1 + e * HD;
    float bj[4];
    #pragma unroll
    for (int j = 0; j < 4; ++j) bj[j] = b1[w * 64 + j * 16 + r16];
    #pragma unroll
    for (int mt = 0; mt < 4; ++mt)
      #pragma unroll
      for (int j = 0; j < 4; ++j)
        #pragma unroll
        for (int r = 0; r < 4; ++r) {
          int row = mt * 16 + g * 4 + r;
          int col = w * 64 + j * 16 + r16;
          float v = mishf(acc[mt][j][r] + bj[j]);
          u16 h = f2bf(v);
          int ec = col ^ ((row & 7) << 3);
          sHi[row * 256 + ec] = h;
          sLo[row * 256 + ec] = f2bf(v - bf2f(h));
        }
  }
  __syncthreads();

  // ---- layers 2 & 3: K=256, A from swizzled LDS planes ----
  #pragma unroll 1
  for (int L = 0; L < 2; ++L) {
    const u16* Wb = (L == 0 ? eW2b : eW3b) + (size_t)e * 131072;
    const float* bb = (L == 0 ? eb2 : eb3) + e * HD;
    f4v a2[4][4];
    #pragma unroll
    for (int i = 0; i < 4; ++i)
      #pragma unroll
      for (int j = 0; j < 4; ++j) a2[i][j] = (f4v){0.f, 0.f, 0.f, 0.f};
    #pragma unroll 2
    for (int s = 0; s < 8; ++s) {
      s8v ah[4], al[4], bh[4], bl[4];
      #pragma unroll
      for (int mt = 0; mt < 4; ++mt) {
        int row = mt * 16 + r16;
        int ec = (s * 32 + g * 8) ^ swz;
        ah[mt] = *(const s8v*)&sHi[row * 256 + ec];
        al[mt] = *(const s8v*)&sLo[row * 256 + ec];
      }
      #pragma unroll
      for (int j = 0; j < 4; ++j) {
        const u16* pb = Wb + (size_t)((s * 16 + w * 4 + j) * 2) * 512 + l * 8;
        bh[j] = *(const s8v*)pb;
        bl[j] = *(const s8v*)(pb + 512);
      }
      #pragma unroll
      for (int mt = 0; mt < 4; ++mt)
        #pragma unroll
        for (int j = 0; j < 4; ++j) {
          a2[mt][j] = mfma16(ah[mt], bh[j], a2[mt][j]);
          a2[mt][j] = mfma16(al[mt], bh[j], a2[mt][j]);
          a2[mt][j] = mfma16(ah[mt], bl[j], a2[mt][j]);
        }
    }
    __syncthreads();  // all reads of previous acts complete
    float bj[4];
    #pragma unroll
    for (int j = 0; j < 4; ++j) bj[j] = bb[w * 64 + j * 16 + r16];
    #pragma unroll
    for (int mt = 0; mt < 4; ++mt)
      #pragma unroll
      for (int j = 0; j < 4; ++j)
        #pragma unroll
        for (int r = 0; r < 4; ++r) {
          int row = mt * 16 + g * 4 + r;
          int col = w * 64 + j * 16 + r16;
          float v = mishf(a2[mt][j][r] + bj[j]);
          u16 h = f2bf(v);
          int ec = col ^ ((row & 7) << 3);
          sHi[row * 256 + ec] = h;
          sLo[row * 256 + ec] = f2bf(v - bf2f(h));
        }
    __syncthreads();
  }

  // ---- final projection: K=256 -> N=64, wave w owns cols w*16..w*16+15 ----
  f4v a3[4];
  #pragma unroll
  for (int i = 0; i < 4; ++i) a3[i] = (f4v){0.f, 0.f, 0.f, 0.f};
  #pragma unroll 2
  for (int s = 0; s < 8; ++s) {
    s8v ah[4], al[4];
    #pragma unroll
    for (int mt = 0; mt < 4; ++mt) {
      int row = mt * 16 + r16;
      int ec = (s * 32 + g * 8) ^ swz;
      ah[mt] = *(const s8v*)&sHi[row * 256 + ec];
      al[mt] = *(const s8v*)&sLo[row * 256 + ec];
    }
    const u16* pb = fWb + (size_t)((s * 4 + w) * 2) * 512 + l * 8;
    s8v bh = *(const s8v*)pb;
    s8v bl = *(const s8v*)(pb + 512);
    #pragma unroll
    for (int mt = 0; mt < 4; ++mt) {
      a3[mt] = mfma16(ah[mt], bh, a3[mt]);
      a3[mt] = mfma16(al[mt], bh, a3[mt]);
      a3[mt] = mfma16(ah[mt], bl, a3[mt]);
    }
  }
  #pragma unroll
  for (int mt = 0; mt < 4; ++mt)
    #pragma unroll
    for (int r = 0; r < 4; ++r) {
      int rl = mt * 16 + g * 4 + r;
      if (rl < nr) {
        float v = a3[mt][r] * sWv[rl];
        atomicAdd(&out[(size_t)sRows[rl] * AD + w * 16 + r16], v);
      }
    }
}

// ---------------- epilogue ----------------
__global__ void k_final(const float* __restrict__ x, const float* __restrict__ sigma,
                        const float* __restrict__ fb, float* __restrict__ out) {
  int i = blockIdx.x * 256 + threadIdx.x;
  if (i >= BN * AD) return;
  int row = i >> 6, c = i & 63;
  float sg = sigma[row];
  float sm = sg - 0.002f;
  float c_skip = 0.25f / (sm * sm + 0.25f);
  float c_out = sm * 0.5f * rsqrtf(sg * sg + 0.25f);
  float d = c_out * (out[i] + fb[c]) + c_skip * x[i];
  out[i] = fminf(fmaxf(d, -1.f), 1.f);
}

extern "C" void kernel_launch(void* const* d_in, const int* in_sizes, int n_in,
                              void* d_out, int out_size, void* d_ws, size_t ws_size,
                              hipStream_t stream) {
  const float* x     = (const float*)d_in[0];
  const float* sigma = (const float*)d_in[1];
  const float* state = (const float*)d_in[2];
  const float* tW1   = (const float*)d_in[3];
  const float* tb1   = (const float*)d_in[4];
  const float* tW2   = (const float*)d_in[5];
  const float* tb2   = (const float*)d_in[6];
  const float* gW1   = (const float*)d_in[7];
  const float* gb1   = (const float*)d_in[8];
  const float* gW2   = (const float*)d_in[9];
  const float* gb2   = (const float*)d_in[10];
  const float* eW1   = (const float*)d_in[11];
  const float* eb1   = (const float*)d_in[12];
  const float* eW2   = (const float*)d_in[13];
  const float* eb2   = (const float*)d_in[14];
  const float* eW3   = (const float*)d_in[15];
  const float* eb3   = (const float*)d_in[16];
  const float* fW    = (const float*)d_in[17];
  const float* fb    = (const float*)d_in[18];
  float* out = (float*)d_out;

  char* p = (char*)d_ws;
  auto alloc = [&](size_t bytes) { void* r = (void*)p; p += (bytes + 255) & ~(size_t)255; return r; };
  u16* inpHi  = (u16*)alloc((size_t)BN * INDP * 2);
  u16* inpLo  = (u16*)alloc((size_t)BN * INDP * 2);
  u16* inpMid = (u16*)alloc((size_t)BN * INDP * 2);
  u16* gW1b   = (u16*)alloc((size_t)11 * 16 * 3 * 512 * 2);
  u16* eW1b   = (u16*)alloc((size_t)16 * 180224 * 2);
  u16* eW2b   = (u16*)alloc((size_t)16 * 131072 * 2);
  u16* eW3b   = (u16*)alloc((size_t)16 * 131072 * 2);
  u16* fWb    = (u16*)alloc((size_t)32768 * 2);
  int*   topk_idx = (int*)alloc((size_t)BN * 4 * 4);
  float* topk_w   = (float*)alloc((size_t)BN * 4 * 4);
  int*   counts   = (int*)alloc(64);
  int*   cursor   = (int*)alloc(64);
  int*   offsets  = (int*)alloc(68);
  int*   tbk      = (int*)alloc(68);
  float* ent      = (float*)alloc(4);
  int*   slot_row = (int*)alloc((size_t)STOT * 4);
  float* slot_w   = (float*)alloc((size_t)STOT * 4);

  k_init<<<(BN * AD + 255) / 256, 256, 0, stream>>>(out, counts, cursor, ent);

  int tot;
  tot = 16 * 11 * 16 * 64;  // experts layer 1
  k_prep<<<(tot + 255) / 256, 256, 0, stream>>>(eW1, eW1b, 336, 11, 16, 256,
                                                (long)336 * 256, 180224, 2, tot);
  tot = 16 * 8 * 16 * 64;   // experts layers 2, 3
  k_prep<<<(tot + 255) / 256, 256, 0, stream>>>(eW2, eW2b, 256, 8, 16, 256,
                                                (long)256 * 256, 131072, 2, tot);
  k_prep<<<(tot + 255) / 256, 256, 0, stream>>>(eW3, eW3b, 256, 8, 16, 256,
                                                (long)256 * 256, 131072, 2, tot);
  tot = 11 * 16 * 64;       // gate layer 1 (3 planes)
  k_prep<<<(tot + 255) / 256, 256, 0, stream>>>(gW1, gW1b, 336, 11, 16, 256,
                                                0, 0, 3, tot);
  tot = 8 * 4 * 64;         // final projection
  k_prep<<<(tot + 255) / 256, 256, 0, stream>>>(fW, fWb, 256, 8, 4, 64,
                                                0, 0, 2, tot);

  k_time_inp<<<BN / 4, 256, 0, stream>>>(x, sigma, state, tW1, tb1, tW2, tb2,
                                         inpHi, inpLo, inpMid);
  k_gate<<<BN / TM, 256, 0, stream>>>(inpHi, inpLo, inpMid, gW1b, gb1, gW2, gb2,
                                      topk_idx, topk_w, counts, ent);
  k_aux<<<1, 64, 0, stream>>>(counts, ent, offsets, tbk, out + (size_t)BN * AD);
  k_scatter<<<BN / 256, 256, 0, stream>>>(topk_idx, topk_w, offsets, cursor, slot_row, slot_w);
  k_expert<<<STOT / TM + EN, 256, 0, stream>>>(inpHi, inpLo, eW1b, eb1, eW2b, eb2,
                                               eW3b, eb3, fWb, offsets, counts, tbk,
                                               slot_row, slot_w, out);
  k_final<<<(BN * AD + 255) / 256, 256, 0, stream>>>(x, sigma, fb, out);
}

// Round 4
// 521.715 us; speedup vs baseline: 5.8422x; 1.0218x over previous
//
#include <hip/hip_runtime.h>
#include <math.h>

#define BN 32768
#define INDP 352      // padded input width (336 -> 352, zero-filled)
#define HD 256
#define AD 64
#define EN 16
#define TM 64
#define STOT (BN * 4)
#define LDP 264       // LDS row stride in u16 (528 B = 132 dwords = 4 mod 32 banks)
#define GRID_E 2072   // 8 * 259, >= max tiles (2064)
#define CHUNK_E 259

typedef __attribute__((ext_vector_type(8))) short s8v;
typedef __attribute__((ext_vector_type(4))) float f4v;
typedef unsigned short u16;

__device__ __forceinline__ u16 f2bf(float x) {
  unsigned u = __float_as_uint(x);
  return (u16)((u + 0x7fffu + ((u >> 16) & 1u)) >> 16);
}
__device__ __forceinline__ float bf2f(u16 h) { return __uint_as_float(((unsigned)h) << 16); }
__device__ __forceinline__ float rcpf(float a) { float r; asm("v_rcp_f32 %0, %1" : "=v"(r) : "v"(a)); return r; }
// mish(x) = x*tanh(softplus(x)) = x*(u^2+2u)/(u^2+2u+2), u=e^x (exact algebraic rewrite)
__device__ __forceinline__ float mishf(float x) {
  float xc = fminf(x, 30.f);
  float u = __expf(xc);
  float w = fmaf(u, u, u + u);
  return x * w * rcpf(w + 2.f);
}
__device__ __forceinline__ f4v mfma16(s8v a, s8v b, f4v c) {
  return __builtin_amdgcn_mfma_f32_16x16x32_bf16(a, b, c, 0, 0, 0);
}
__device__ __forceinline__ void pack8(const u16* q, u16* d) {
  uint4 u;
  u.x = q[0] | ((unsigned)q[1] << 16); u.y = q[2] | ((unsigned)q[3] << 16);
  u.z = q[4] | ((unsigned)q[5] << 16); u.w = q[6] | ((unsigned)q[7] << 16);
  *(uint4*)d = u;
}

// ---------------- init ----------------
__global__ void k_init(float* __restrict__ out, int* __restrict__ counts,
                       int* __restrict__ cursor, float* __restrict__ ent) {
  int i = blockIdx.x * 256 + threadIdx.x;
  if (i < BN * AD) out[i] = 0.f;
  if (i < 16) { counts[i] = 0; cursor[i] = 0; }
  if (i == 16) *ent = 0.f;
}

// ------- weight prep: fp32 [K][N] -> fragment-ordered split-bf16 planes -------
// dst (u16 units): [s][nt][plane 0..NP-1][lane 0..63][8]; elem i of lane l:
//   k = s*32 + 8*(l>>4) + i, n = nt*16 + (l&15)
__global__ void k_prep(const float* __restrict__ src, u16* __restrict__ dst,
                       int Ksrc, int Spad, int NT, int N,
                       long sStride, long dStride, int NP, int total) {
  int idx = blockIdx.x * 256 + threadIdx.x;
  if (idx >= total) return;
  int l = idx & 63;
  int t = idx >> 6;
  int nt = t % NT; t /= NT;
  int s = t % Spad; t /= Spad;
  int m = t;
  const float* sp = src + (size_t)m * sStride;
  int n = nt * 16 + (l & 15);
  int kb = s * 32 + (l >> 4) * 8;
  u16 q0[8], q1[8], q2[8];
  #pragma unroll
  for (int i = 0; i < 8; ++i) {
    int k = kb + i;
    float v = (k < Ksrc) ? sp[(size_t)k * N + n] : 0.f;
    u16 a = f2bf(v); float r1 = v - bf2f(a);
    u16 b = f2bf(r1); float r2 = r1 - bf2f(b);
    q0[i] = a; q1[i] = b; q2[i] = f2bf(r2);
  }
  u16* d = dst + (size_t)m * dStride + (size_t)((s * NT + nt) * NP) * 512 + l * 8;
  pack8(q0, d);
  pack8(q1, d + 512);
  if (NP == 3) pack8(q2, d + 1024);
}

// ------- time embedding + input assembly (3 split-bf16 planes) -------
__global__ void k_time_inp(const float* __restrict__ x, const float* __restrict__ sigma,
                           const float* __restrict__ state,
                           const float* __restrict__ tW1, const float* __restrict__ tb1,
                           const float* __restrict__ tW2, const float* __restrict__ tb2,
                           u16* __restrict__ p0, u16* __restrict__ p1, u16* __restrict__ p2) {
  const int wv = threadIdx.x >> 6;
  const int lane = threadIdx.x & 63;
  const int row = blockIdx.x * 4 + wv;
  const float sg = sigma[row];
  const float rt = 250.0f * logf(sg + 1e-44f);
  float pe = 0.f;
  if (lane < 16) {
    int j = lane & 7;
    float f = expf(-1.3157629102823121f * (float)j);  // -ln(10000)/7 * j
    float ang = rt * f;
    pe = (lane < 8) ? sinf(ang) : cosf(ang);
  }
  float h1;
  {
    float acc = 0.f;
    int j = lane & 31;
    #pragma unroll
    for (int i = 0; i < 16; ++i) {
      float p = __shfl(pe, i, 64);
      acc = fmaf(p, tW1[i * 32 + j], acc);
    }
    acc += tb1[j];
    float sp = log1pf(expf(acc));
    h1 = acc * tanhf(sp);
  }
  float t2;
  {
    float acc = 0.f;
    int j = lane & 15;
    #pragma unroll
    for (int i = 0; i < 32; ++i) {
      float h = __shfl(h1, i, 64);
      acc = fmaf(h, tW2[i * 16 + j], acc);
    }
    t2 = acc + tb2[j];
  }
  const float c_in = rsqrtf(sg * sg + 0.25f);
  u16* r0 = p0 + (size_t)row * INDP;
  u16* r1 = p1 + (size_t)row * INDP;
  u16* r2 = p2 + (size_t)row * INDP;
  auto wsplit = [&](int c, float v) {
    u16 a = f2bf(v); float ra = v - bf2f(a);
    u16 b = f2bf(ra); float rb = ra - bf2f(b);
    r0[c] = a; r1[c] = b; r2[c] = f2bf(rb);
  };
  wsplit(lane, c_in * x[row * 64 + lane]);
  if (lane < 16) wsplit(64 + lane, t2);
  #pragma unroll
  for (int r = 0; r < 4; ++r)
    wsplit(80 + r * 64 + lane, state[(size_t)row * 256 + r * 64 + lane]);
  if (lane < 16) { r0[336 + lane] = 0; r1[336 + lane] = 0; r2[336 + lane] = 0; }
}

// ------- gate: 6-term split MFMA layer1 (fp32-grade) + relu + 256->16 + softmax + top4 -------
__global__ __launch_bounds__(256) void k_gate(
    const u16* __restrict__ p0, const u16* __restrict__ p1, const u16* __restrict__ p2,
    const u16* __restrict__ gW1b, const float* __restrict__ gb1,
    const float* __restrict__ gW2, const float* __restrict__ gb2,
    int* __restrict__ topk_idx, float* __restrict__ topk_w,
    int* __restrict__ counts, float* __restrict__ ent_sum) {
  __shared__ float sH[TM * 257];
  __shared__ float sB2[256 * 16];
  __shared__ float sLog[TM * 16];
  __shared__ int scnt[16];
  const int tid = threadIdx.x;
  const int l = tid & 63, w = tid >> 6;
  const int g = l >> 4, r16 = l & 15;
  const int row0 = blockIdx.x * TM;
  if (tid < 16) scnt[tid] = 0;

  f4v acc[4][4];
  #pragma unroll
  for (int i = 0; i < 4; ++i)
    #pragma unroll
    for (int j = 0; j < 4; ++j) acc[i][j] = (f4v){0.f, 0.f, 0.f, 0.f};

  for (int s = 0; s < 11; ++s) {
    s8v a0[4], a1[4], a2[4], b0[4], b1[4], b2[4];
    #pragma unroll
    for (int mt = 0; mt < 4; ++mt) {
      size_t off = (size_t)(row0 + mt * 16 + r16) * INDP + s * 32 + g * 8;
      a0[mt] = *(const s8v*)(p0 + off);
      a1[mt] = *(const s8v*)(p1 + off);
      a2[mt] = *(const s8v*)(p2 + off);
    }
    #pragma unroll
    for (int j = 0; j < 4; ++j) {
      const u16* pb = gW1b + (size_t)((s * 16 + w * 4 + j) * 3) * 512 + l * 8;
      b0[j] = *(const s8v*)pb;
      b1[j] = *(const s8v*)(pb + 512);
      b2[j] = *(const s8v*)(pb + 1024);
    }
    #pragma unroll
    for (int mt = 0; mt < 4; ++mt)
      #pragma unroll
      for (int j = 0; j < 4; ++j) {
        acc[mt][j] = mfma16(a0[mt], b0[j], acc[mt][j]);
        acc[mt][j] = mfma16(a0[mt], b1[j], acc[mt][j]);
        acc[mt][j] = mfma16(a1[mt], b0[j], acc[mt][j]);
        acc[mt][j] = mfma16(a1[mt], b1[j], acc[mt][j]);
        acc[mt][j] = mfma16(a0[mt], b2[j], acc[mt][j]);
        acc[mt][j] = mfma16(a2[mt], b0[j], acc[mt][j]);
      }
  }
  float bj[4];
  #pragma unroll
  for (int j = 0; j < 4; ++j) bj[j] = gb1[w * 64 + j * 16 + r16];
  #pragma unroll
  for (int mt = 0; mt < 4; ++mt)
    #pragma unroll
    for (int j = 0; j < 4; ++j)
      #pragma unroll
      for (int r = 0; r < 4; ++r) {
        int row = mt * 16 + g * 4 + r;
        sH[row * 257 + w * 64 + j * 16 + r16] = fmaxf(acc[mt][j][r] + bj[j], 0.f);
      }
  #pragma unroll
  for (int it = 0; it < 4; ++it) {
    int idx = tid + it * 256;
    *(float4*)&sB2[idx * 4] = *(const float4*)(gW2 + (size_t)idx * 4);
  }
  __syncthreads();
  {
    const int rr = tid >> 2, q = tid & 3;
    float g0 = 0.f, g1 = 0.f, g2 = 0.f, g3 = 0.f;
    for (int k = 0; k < 256; ++k) {
      float a = sH[rr * 257 + k];
      float4 bv = *(const float4*)&sB2[k * 16 + q * 4];
      g0 = fmaf(a, bv.x, g0); g1 = fmaf(a, bv.y, g1);
      g2 = fmaf(a, bv.z, g2); g3 = fmaf(a, bv.w, g3);
    }
    sLog[rr * 16 + q * 4 + 0] = g0 + gb2[q * 4 + 0];
    sLog[rr * 16 + q * 4 + 1] = g1 + gb2[q * 4 + 1];
    sLog[rr * 16 + q * 4 + 2] = g2 + gb2[q * 4 + 2];
    sLog[rr * 16 + q * 4 + 3] = g3 + gb2[q * 4 + 3];
  }
  __syncthreads();
  float entc = 0.f;
  if (tid < 64) {
    const int row = row0 + tid;
    float gx[16], mx = -1e30f;
    #pragma unroll
    for (int e = 0; e < 16; ++e) { gx[e] = sLog[tid * 16 + e]; mx = fmaxf(mx, gx[e]); }
    float p[16], s = 0.f;
    #pragma unroll
    for (int e = 0; e < 16; ++e) { p[e] = expf(gx[e] - mx); s += p[e]; }
    const float inv = 1.f / s;
    #pragma unroll
    for (int e = 0; e < 16; ++e) {
      float pr = p[e] * inv;
      entc -= pr * logf(pr + 1e-9f);
    }
    int idxs[4]; float scs[4];
    unsigned used = 0;
    float wsum = 1e-9f;
    #pragma unroll
    for (int k = 0; k < 4; ++k) {
      int be = 0; float bv = -1.f;
      #pragma unroll
      for (int e = 0; e < 16; ++e) {
        float pr = p[e] * inv;
        if (!((used >> e) & 1u) && pr > bv) { bv = pr; be = e; }
      }
      used |= (1u << be);
      idxs[k] = be; scs[k] = bv;
      wsum += bv;
    }
    #pragma unroll
    for (int k = 0; k < 4; ++k) {
      topk_idx[row * 4 + k] = idxs[k];
      topk_w[row * 4 + k] = scs[k] / wsum;
      atomicAdd(&scnt[idxs[k]], 1);
    }
    #pragma unroll
    for (int off = 32; off > 0; off >>= 1) entc += __shfl_down(entc, off, 64);
  }
  __syncthreads();
  if (tid == 0) atomicAdd(ent_sum, entc);
  if (tid < 16 && scnt[tid] > 0) atomicAdd(&counts[tid], scnt[tid]);
}

// ---------------- offsets + aux loss ----------------
__global__ void k_aux(const int* __restrict__ counts, const float* __restrict__ ent_sum,
                      int* __restrict__ offsets, int* __restrict__ tbk,
                      float* __restrict__ aux_out) {
  if (threadIdx.x == 0) {
    int off = 0, t = 0;
    float load[16], mean = 0.f;
    for (int e = 0; e < 16; ++e) {
      offsets[e] = off; tbk[e] = t;
      int c = counts[e];
      off += c;
      t += (c + TM - 1) / TM;
      load[e] = (float)c / (32768.0f + 1e-9f);
      mean += load[e];
    }
    offsets[16] = off; tbk[16] = t;
    mean *= (1.f / 16.f);
    float var = 0.f;
    for (int e = 0; e < 16; ++e) { float d = load[e] - mean; var += d * d; }
    var *= (1.f / 15.f);
    *aux_out = var + ent_sum[0] * (1.0f / 32768.0f);
  }
}

// ------- scatter: block-aggregated (16 global atomics per block) -------
__global__ void k_scatter(const int* __restrict__ topk_idx, const float* __restrict__ topk_w,
                          const int* __restrict__ offsets, int* __restrict__ cursor,
                          int* __restrict__ slot_row, float* __restrict__ slot_w) {
  __shared__ int cnt[16];
  __shared__ int base[16];
  const int tid = threadIdx.x;
  if (tid < 16) cnt[tid] = 0;
  __syncthreads();
  const int row = blockIdx.x * 256 + tid;
  int e4[4]; float w4[4]; int lp[4];
  #pragma unroll
  for (int k = 0; k < 4; ++k) {
    e4[k] = topk_idx[row * 4 + k];
    w4[k] = topk_w[row * 4 + k];
    lp[k] = atomicAdd(&cnt[e4[k]], 1);
  }
  __syncthreads();
  if (tid < 16) base[tid] = atomicAdd(&cursor[tid], cnt[tid]);
  __syncthreads();
  #pragma unroll
  for (int k = 0; k < 4; ++k) {
    int s = offsets[e4[k]] + base[e4[k]] + lp[k];
    slot_row[s] = row;
    slot_w[s] = w4[k];
  }
}

// ------- fused expert: 3 MFMA layers + fW, 3-term split-bf16 -------
// 512 threads = 8 waves (2 M-groups x 4 N-groups); 2 blocks/CU -> 16 waves/CU.
__global__ __launch_bounds__(512, 4) void k_expert(
    const u16* __restrict__ inpHi, const u16* __restrict__ inpLo,
    const u16* __restrict__ eW1b, const float* __restrict__ eb1,
    const u16* __restrict__ eW2b, const float* __restrict__ eb2,
    const u16* __restrict__ eW3b, const float* __restrict__ eb3,
    const u16* __restrict__ fWb,
    const int* __restrict__ offsets, const int* __restrict__ counts,
    const int* __restrict__ tbk, const int* __restrict__ slot_row,
    const float* __restrict__ slot_w, float* __restrict__ out) {
  __shared__ __align__(16) u16 sHi[TM * LDP];
  __shared__ __align__(16) u16 sLo[TM * LDP];
  __shared__ int sRows[TM];
  __shared__ float sWv[TM];

  // XCD-chunked bijective remap: physical round-robin -> contiguous chunks/XCD
  const int bid = (blockIdx.x & 7) * CHUNK_E + (blockIdx.x >> 3);
  if (bid >= tbk[16]) return;
  int e = 0;
  #pragma unroll
  for (int i = 1; i < 16; ++i)
    if (bid >= tbk[i]) e = i;
  const int tile = bid - tbk[e];
  const int cnt = counts[e];
  const int s0 = offsets[e] + tile * TM;
  const int nr = min(TM, cnt - tile * TM);
  const int tid = threadIdx.x;
  const int l = tid & 63;
  const int w8 = tid >> 6;          // 0..7
  const int wm = w8 >> 2;           // 0..1  (M half)
  const int wn = w8 & 3;            // 0..3  (N quarter)
  const int g = l >> 4, r16 = l & 15;
  const int swz = (r16 & 7) << 3;   // XOR swizzle (16B granules) for A-row reads

  if (tid < TM) {
    sRows[tid] = (tid < nr) ? slot_row[s0 + tid] : slot_row[s0];
    sWv[tid] = (tid < nr) ? slot_w[s0 + tid] : 0.f;
  }
  __syncthreads();

  size_t rbase[2];
  #pragma unroll
  for (int mt = 0; mt < 2; ++mt)
    rbase[mt] = (size_t)sRows[(wm * 2 + mt) * 16 + r16] * INDP;

  f4v acc[2][4];
  #pragma unroll
  for (int i = 0; i < 2; ++i)
    #pragma unroll
    for (int j = 0; j < 4; ++j) acc[i][j] = (f4v){0.f, 0.f, 0.f, 0.f};

  // ---- layer 1: K=352, A direct from global planes ----
  const u16* W1 = eW1b + (size_t)e * 180224;
  for (int s = 0; s < 11; ++s) {
    s8v ah[2], al[2], bh[4], bl[4];
    #pragma unroll
    for (int mt = 0; mt < 2; ++mt) {
      size_t off = rbase[mt] + s * 32 + g * 8;
      ah[mt] = *(const s8v*)(inpHi + off);
      al[mt] = *(const s8v*)(inpLo + off);
    }
    #pragma unroll
    for (int j = 0; j < 4; ++j) {
      const u16* pb = W1 + (size_t)((s * 16 + wn * 4 + j) * 2) * 512 + l * 8;
      bh[j] = *(const s8v*)pb;
      bl[j] = *(const s8v*)(pb + 512);
    }
    #pragma unroll
    for (int mt = 0; mt < 2; ++mt)
      #pragma unroll
      for (int j = 0; j < 4; ++j) {
        acc[mt][j] = mfma16(ah[mt], bh[j], acc[mt][j]);
        acc[mt][j] = mfma16(al[mt], bh[j], acc[mt][j]);
        acc[mt][j] = mfma16(ah[mt], bl[j], acc[mt][j]);
      }
  }
  {
    const float* b1 = eb1 + e * HD;
    float bj[4];
    #pragma unroll
    for (int j = 0; j < 4; ++j) bj[j] = b1[wn * 64 + j * 16 + r16];
    #pragma unroll
    for (int mt = 0; mt < 2; ++mt)
      #pragma unroll
      for (int j = 0; j < 4; ++j)
        #pragma unroll
        for (int r = 0; r < 4; ++r) {
          int row = (wm * 2 + mt) * 16 + g * 4 + r;
          int col = wn * 64 + j * 16 + r16;
          float v = mishf(acc[mt][j][r] + bj[j]);
          u16 h = f2bf(v);
          int ec = col ^ ((row & 7) << 3);
          sHi[row * LDP + ec] = h;
          sLo[row * LDP + ec] = f2bf(v - bf2f(h));
        }
  }
  __syncthreads();

  // ---- layers 2 & 3: K=256, A from swizzled LDS planes ----
  #pragma unroll 1
  for (int L = 0; L < 2; ++L) {
    const u16* Wb = (L == 0 ? eW2b : eW3b) + (size_t)e * 131072;
    const float* bb = (L == 0 ? eb2 : eb3) + e * HD;
    f4v a2[2][4];
    #pragma unroll
    for (int i = 0; i < 2; ++i)
      #pragma unroll
      for (int j = 0; j < 4; ++j) a2[i][j] = (f4v){0.f, 0.f, 0.f, 0.f};
    #pragma unroll 2
    for (int s = 0; s < 8; ++s) {
      s8v ah[2], al[2], bh[4], bl[4];
      #pragma unroll
      for (int mt = 0; mt < 2; ++mt) {
        int row = (wm * 2 + mt) * 16 + r16;
        int ec = (s * 32 + g * 8) ^ swz;
        ah[mt] = *(const s8v*)&sHi[row * LDP + ec];
        al[mt] = *(const s8v*)&sLo[row * LDP + ec];
      }
      #pragma unroll
      for (int j = 0; j < 4; ++j) {
        const u16* pb = Wb + (size_t)((s * 16 + wn * 4 + j) * 2) * 512 + l * 8;
        bh[j] = *(const s8v*)pb;
        bl[j] = *(const s8v*)(pb + 512);
      }
      #pragma unroll
      for (int mt = 0; mt < 2; ++mt)
        #pragma unroll
        for (int j = 0; j < 4; ++j) {
          a2[mt][j] = mfma16(ah[mt], bh[j], a2[mt][j]);
          a2[mt][j] = mfma16(al[mt], bh[j], a2[mt][j]);
          a2[mt][j] = mfma16(ah[mt], bl[j], a2[mt][j]);
        }
    }
    __syncthreads();  // all reads of previous acts complete
    float bj[4];
    #pragma unroll
    for (int j = 0; j < 4; ++j) bj[j] = bb[wn * 64 + j * 16 + r16];
    #pragma unroll
    for (int mt = 0; mt < 2; ++mt)
      #pragma unroll
      for (int j = 0; j < 4; ++j)
        #pragma unroll
        for (int r = 0; r < 4; ++r) {
          int row = (wm * 2 + mt) * 16 + g * 4 + r;
          int col = wn * 64 + j * 16 + r16;
          float v = mishf(a2[mt][j][r] + bj[j]);
          u16 h = f2bf(v);
          int ec = col ^ ((row & 7) << 3);
          sHi[row * LDP + ec] = h;
          sLo[row * LDP + ec] = f2bf(v - bf2f(h));
        }
    __syncthreads();
  }

  // ---- final projection: K=256 -> N=64; wave (wm,wn): rows 2 tiles, cols wn*16.. ----
  f4v a3[2];
  #pragma unroll
  for (int i = 0; i < 2; ++i) a3[i] = (f4v){0.f, 0.f, 0.f, 0.f};
  #pragma unroll 2
  for (int s = 0; s < 8; ++s) {
    s8v ah[2], al[2];
    #pragma unroll
    for (int mt = 0; mt < 2; ++mt) {
      int row = (wm * 2 + mt) * 16 + r16;
      int ec = (s * 32 + g * 8) ^ swz;
      ah[mt] = *(const s8v*)&sHi[row * LDP + ec];
      al[mt] = *(const s8v*)&sLo[row * LDP + ec];
    }
    const u16* pb = fWb + (size_t)((s * 4 + wn) * 2) * 512 + l * 8;
    s8v bh = *(const s8v*)pb;
    s8v bl = *(const s8v*)(pb + 512);
    #pragma unroll
    for (int mt = 0; mt < 2; ++mt) {
      a3[mt] = mfma16(ah[mt], bh, a3[mt]);
      a3[mt] = mfma16(al[mt], bh, a3[mt]);
      a3[mt] = mfma16(ah[mt], bl, a3[mt]);
    }
  }
  #pragma unroll
  for (int mt = 0; mt < 2; ++mt)
    #pragma unroll
    for (int r = 0; r < 4; ++r) {
      int rl = (wm * 2 + mt) * 16 + g * 4 + r;
      if (rl < nr) {
        float v = a3[mt][r] * sWv[rl];
        atomicAdd(&out[(size_t)sRows[rl] * AD + wn * 16 + r16], v);
      }
    }
}

// ---------------- epilogue ----------------
__global__ void k_final(const float* __restrict__ x, const float* __restrict__ sigma,
                        const float* __restrict__ fb, float* __restrict__ out) {
  int i = blockIdx.x * 256 + threadIdx.x;
  if (i >= BN * AD) return;
  int row = i >> 6, c = i & 63;
  float sg = sigma[row];
  float sm = sg - 0.002f;
  float c_skip = 0.25f / (sm * sm + 0.25f);
  float c_out = sm * 0.5f * rsqrtf(sg * sg + 0.25f);
  float d = c_out * (out[i] + fb[c]) + c_skip * x[i];
  out[i] = fminf(fmaxf(d, -1.f), 1.f);
}

extern "C" void kernel_launch(void* const* d_in, const int* in_sizes, int n_in,
                              void* d_out, int out_size, void* d_ws, size_t ws_size,
                              hipStream_t stream) {
  const float* x     = (const float*)d_in[0];
  const float* sigma = (const float*)d_in[1];
  const float* state = (const float*)d_in[2];
  const float* tW1   = (const float*)d_in[3];
  const float* tb1   = (const float*)d_in[4];
  const float* tW2   = (const float*)d_in[5];
  const float* tb2   = (const float*)d_in[6];
  const float* gW1   = (const float*)d_in[7];
  const float* gb1   = (const float*)d_in[8];
  const float* gW2   = (const float*)d_in[9];
  const float* gb2   = (const float*)d_in[10];
  const float* eW1   = (const float*)d_in[11];
  const float* eb1   = (const float*)d_in[12];
  const float* eW2   = (const float*)d_in[13];
  const float* eb2   = (const float*)d_in[14];
  const float* eW3   = (const float*)d_in[15];
  const float* eb3   = (const float*)d_in[16];
  const float* fW    = (const float*)d_in[17];
  const float* fb    = (const float*)d_in[18];
  float* out = (float*)d_out;

  char* p = (char*)d_ws;
  auto alloc = [&](size_t bytes) { void* r = (void*)p; p += (bytes + 255) & ~(size_t)255; return r; };
  u16* inpHi  = (u16*)alloc((size_t)BN * INDP * 2);
  u16* inpLo  = (u16*)alloc((size_t)BN * INDP * 2);
  u16* inpMid = (u16*)alloc((size_t)BN * INDP * 2);
  u16* gW1b   = (u16*)alloc((size_t)11 * 16 * 3 * 512 * 2);
  u16* eW1b   = (u16*)alloc((size_t)16 * 180224 * 2);
  u16* eW2b   = (u16*)alloc((size_t)16 * 131072 * 2);
  u16* eW3b   = (u16*)alloc((size_t)16 * 131072 * 2);
  u16* fWb    = (u16*)alloc((size_t)32768 * 2);
  int*   topk_idx = (int*)alloc((size_t)BN * 4 * 4);
  float* topk_w   = (float*)alloc((size_t)BN * 4 * 4);
  int*   counts   = (int*)alloc(64);
  int*   cursor   = (int*)alloc(64);
  int*   offsets  = (int*)alloc(68);
  int*   tbk      = (int*)alloc(68);
  float* ent      = (float*)alloc(4);
  int*   slot_row = (int*)alloc((size_t)STOT * 4);
  float* slot_w   = (float*)alloc((size_t)STOT * 4);

  k_init<<<(BN * AD + 255) / 256, 256, 0, stream>>>(out, counts, cursor, ent);

  int tot;
  tot = 16 * 11 * 16 * 64;  // experts layer 1
  k_prep<<<(tot + 255) / 256, 256, 0, stream>>>(eW1, eW1b, 336, 11, 16, 256,
                                                (long)336 * 256, 180224, 2, tot);
  tot = 16 * 8 * 16 * 64;   // experts layers 2, 3
  k_prep<<<(tot + 255) / 256, 256, 0, stream>>>(eW2, eW2b, 256, 8, 16, 256,
                                                (long)256 * 256, 131072, 2, tot);
  k_prep<<<(tot + 255) / 256, 256, 0, stream>>>(eW3, eW3b, 256, 8, 16, 256,
                                                (long)256 * 256, 131072, 2, tot);
  tot = 11 * 16 * 64;       // gate layer 1 (3 planes)
  k_prep<<<(tot + 255) / 256, 256, 0, stream>>>(gW1, gW1b, 336, 11, 16, 256,
                                                0, 0, 3, tot);
  tot = 8 * 4 * 64;         // final projection
  k_prep<<<(tot + 255) / 256, 256, 0, stream>>>(fW, fWb, 256, 8, 4, 64,
                                                0, 0, 2, tot);

  k_time_inp<<<BN / 4, 256, 0, stream>>>(x, sigma, state, tW1, tb1, tW2, tb2,
                                         inpHi, inpLo, inpMid);
  k_gate<<<BN / TM, 256, 0, stream>>>(inpHi, inpLo, inpMid, gW1b, gb1, gW2, gb2,
                                      topk_idx, topk_w, counts, ent);
  k_aux<<<1, 64, 0, stream>>>(counts, ent, offsets, tbk, out + (size_t)BN * AD);
  k_scatter<<<BN / 256, 256, 0, stream>>>(topk_idx, topk_w, offsets, cursor, slot_row, slot_w);
  k_expert<<<GRID_E, 512, 0, stream>>>(inpHi, inpLo, eW1b, eb1, eW2b, eb2,
                                       eW3b, eb3, fWb, offsets, counts, tbk,
                                       slot_row, slot_w, out);
  k_final<<<(BN * AD + 255) / 256, 256, 0, stream>>>(x, sigma, fb, out);
}

// Round 5
// 521.393 us; speedup vs baseline: 5.8458x; 1.0006x over previous
//
#include <hip/hip_runtime.h>
#include <math.h>

#define BN 32768
#define INDP 352      // padded input width (336 -> 352, zero-filled)
#define HD 256
#define AD 64
#define EN 16
#define TM 64
#define STOT (BN * 4)
#define LDP 256       // LDS row stride in u16 (512B, 0 mod 32 dwords: XOR swizzle alone
                      // gives uniform 8 dwords/bank per wave64 b128 — round-4's 264 broke this)
#define GRID_E 2072   // 8 * 259, >= max tiles (2064)
#define CHUNK_E 259

typedef __attribute__((ext_vector_type(8))) short s8v;
typedef __attribute__((ext_vector_type(4))) float f4v;
typedef unsigned short u16;

__device__ __forceinline__ u16 f2bf(float x) {
  unsigned u = __float_as_uint(x);
  return (u16)((u + 0x7fffu + ((u >> 16) & 1u)) >> 16);
}
__device__ __forceinline__ float bf2f(u16 h) { return __uint_as_float(((unsigned)h) << 16); }
__device__ __forceinline__ float rcpf(float a) { float r; asm("v_rcp_f32 %0, %1" : "=v"(r) : "v"(a)); return r; }
// mish(x) = x*tanh(softplus(x)) = x*(u^2+2u)/(u^2+2u+2), u=e^x (exact algebraic rewrite)
__device__ __forceinline__ float mishf(float x) {
  float xc = fminf(x, 30.f);
  float u = __expf(xc);
  float w = fmaf(u, u, u + u);
  return x * w * rcpf(w + 2.f);
}
__device__ __forceinline__ f4v mfma16(s8v a, s8v b, f4v c) {
  return __builtin_amdgcn_mfma_f32_16x16x32_bf16(a, b, c, 0, 0, 0);
}
__device__ __forceinline__ void pack8(const u16* q, u16* d) {
  uint4 u;
  u.x = q[0] | ((unsigned)q[1] << 16); u.y = q[2] | ((unsigned)q[3] << 16);
  u.z = q[4] | ((unsigned)q[5] << 16); u.w = q[6] | ((unsigned)q[7] << 16);
  *(uint4*)d = u;
}

// ---------------- init ----------------
__global__ void k_init(float* __restrict__ out, int* __restrict__ counts,
                       int* __restrict__ cursor, float* __restrict__ ent) {
  int i = blockIdx.x * 256 + threadIdx.x;
  if (i < BN * AD) out[i] = 0.f;
  if (i < 16) { counts[i] = 0; cursor[i] = 0; }
  if (i == 16) *ent = 0.f;
}

// ------- weight prep: fp32 [K][N] -> fragment-ordered split-bf16 planes -------
// dst (u16 units): [s][nt][plane 0..NP-1][lane 0..63][8]; elem i of lane l:
//   k = s*32 + 8*(l>>4) + i, n = nt*16 + (l&15)
__global__ void k_prep(const float* __restrict__ src, u16* __restrict__ dst,
                       int Ksrc, int Spad, int NT, int N,
                       long sStride, long dStride, int NP, int total) {
  int idx = blockIdx.x * 256 + threadIdx.x;
  if (idx >= total) return;
  int l = idx & 63;
  int t = idx >> 6;
  int nt = t % NT; t /= NT;
  int s = t % Spad; t /= Spad;
  int m = t;
  const float* sp = src + (size_t)m * sStride;
  int n = nt * 16 + (l & 15);
  int kb = s * 32 + (l >> 4) * 8;
  u16 q0[8], q1[8], q2[8];
  #pragma unroll
  for (int i = 0; i < 8; ++i) {
    int k = kb + i;
    float v = (k < Ksrc) ? sp[(size_t)k * N + n] : 0.f;
    u16 a = f2bf(v); float r1 = v - bf2f(a);
    u16 b = f2bf(r1); float r2 = r1 - bf2f(b);
    q0[i] = a; q1[i] = b; q2[i] = f2bf(r2);
  }
  u16* d = dst + (size_t)m * dStride + (size_t)((s * NT + nt) * NP) * 512 + l * 8;
  pack8(q0, d);
  pack8(q1, d + 512);
  if (NP == 3) pack8(q2, d + 1024);
}

// ------- time embedding + input assembly (3 split-bf16 planes) -------
__global__ void k_time_inp(const float* __restrict__ x, const float* __restrict__ sigma,
                           const float* __restrict__ state,
                           const float* __restrict__ tW1, const float* __restrict__ tb1,
                           const float* __restrict__ tW2, const float* __restrict__ tb2,
                           u16* __restrict__ p0, u16* __restrict__ p1, u16* __restrict__ p2) {
  const int wv = threadIdx.x >> 6;
  const int lane = threadIdx.x & 63;
  const int row = blockIdx.x * 4 + wv;
  const float sg = sigma[row];
  const float rt = 250.0f * logf(sg + 1e-44f);
  float pe = 0.f;
  if (lane < 16) {
    int j = lane & 7;
    float f = expf(-1.3157629102823121f * (float)j);  // -ln(10000)/7 * j
    float ang = rt * f;
    pe = (lane < 8) ? sinf(ang) : cosf(ang);
  }
  float h1;
  {
    float acc = 0.f;
    int j = lane & 31;
    #pragma unroll
    for (int i = 0; i < 16; ++i) {
      float p = __shfl(pe, i, 64);
      acc = fmaf(p, tW1[i * 32 + j], acc);
    }
    acc += tb1[j];
    float sp = log1pf(expf(acc));
    h1 = acc * tanhf(sp);
  }
  float t2;
  {
    float acc = 0.f;
    int j = lane & 15;
    #pragma unroll
    for (int i = 0; i < 32; ++i) {
      float h = __shfl(h1, i, 64);
      acc = fmaf(h, tW2[i * 16 + j], acc);
    }
    t2 = acc + tb2[j];
  }
  const float c_in = rsqrtf(sg * sg + 0.25f);
  u16* r0 = p0 + (size_t)row * INDP;
  u16* r1 = p1 + (size_t)row * INDP;
  u16* r2 = p2 + (size_t)row * INDP;
  auto wsplit = [&](int c, float v) {
    u16 a = f2bf(v); float ra = v - bf2f(a);
    u16 b = f2bf(ra); float rb = ra - bf2f(b);
    r0[c] = a; r1[c] = b; r2[c] = f2bf(rb);
  };
  wsplit(lane, c_in * x[row * 64 + lane]);
  if (lane < 16) wsplit(64 + lane, t2);
  #pragma unroll
  for (int r = 0; r < 4; ++r)
    wsplit(80 + r * 64 + lane, state[(size_t)row * 256 + r * 64 + lane]);
  if (lane < 16) { r0[336 + lane] = 0; r1[336 + lane] = 0; r2[336 + lane] = 0; }
}

// ------- gate: 6-term split MFMA layer1 (fp32-grade) + relu + 256->16 + softmax + top4 -------
__global__ __launch_bounds__(256) void k_gate(
    const u16* __restrict__ p0, const u16* __restrict__ p1, const u16* __restrict__ p2,
    const u16* __restrict__ gW1b, const float* __restrict__ gb1,
    const float* __restrict__ gW2, const float* __restrict__ gb2,
    int* __restrict__ topk_idx, float* __restrict__ topk_w,
    int* __restrict__ counts, float* __restrict__ ent_sum) {
  __shared__ float sH[TM * 257];
  __shared__ float sB2[256 * 16];
  __shared__ float sLog[TM * 16];
  __shared__ int scnt[16];
  const int tid = threadIdx.x;
  const int l = tid & 63, w = tid >> 6;
  const int g = l >> 4, r16 = l & 15;
  const int row0 = blockIdx.x * TM;
  if (tid < 16) scnt[tid] = 0;

  f4v acc[4][4];
  #pragma unroll
  for (int i = 0; i < 4; ++i)
    #pragma unroll
    for (int j = 0; j < 4; ++j) acc[i][j] = (f4v){0.f, 0.f, 0.f, 0.f};

  for (int s = 0; s < 11; ++s) {
    s8v a0[4], a1[4], a2[4], b0[4], b1[4], b2[4];
    #pragma unroll
    for (int mt = 0; mt < 4; ++mt) {
      size_t off = (size_t)(row0 + mt * 16 + r16) * INDP + s * 32 + g * 8;
      a0[mt] = *(const s8v*)(p0 + off);
      a1[mt] = *(const s8v*)(p1 + off);
      a2[mt] = *(const s8v*)(p2 + off);
    }
    #pragma unroll
    for (int j = 0; j < 4; ++j) {
      const u16* pb = gW1b + (size_t)((s * 16 + w * 4 + j) * 3) * 512 + l * 8;
      b0[j] = *(const s8v*)pb;
      b1[j] = *(const s8v*)(pb + 512);
      b2[j] = *(const s8v*)(pb + 1024);
    }
    #pragma unroll
    for (int mt = 0; mt < 4; ++mt)
      #pragma unroll
      for (int j = 0; j < 4; ++j) {
        acc[mt][j] = mfma16(a0[mt], b0[j], acc[mt][j]);
        acc[mt][j] = mfma16(a0[mt], b1[j], acc[mt][j]);
        acc[mt][j] = mfma16(a1[mt], b0[j], acc[mt][j]);
        acc[mt][j] = mfma16(a1[mt], b1[j], acc[mt][j]);
        acc[mt][j] = mfma16(a0[mt], b2[j], acc[mt][j]);
        acc[mt][j] = mfma16(a2[mt], b0[j], acc[mt][j]);
      }
  }
  float bj[4];
  #pragma unroll
  for (int j = 0; j < 4; ++j) bj[j] = gb1[w * 64 + j * 16 + r16];
  #pragma unroll
  for (int mt = 0; mt < 4; ++mt)
    #pragma unroll
    for (int j = 0; j < 4; ++j)
      #pragma unroll
      for (int r = 0; r < 4; ++r) {
        int row = mt * 16 + g * 4 + r;
        sH[row * 257 + w * 64 + j * 16 + r16] = fmaxf(acc[mt][j][r] + bj[j], 0.f);
      }
  #pragma unroll
  for (int it = 0; it < 4; ++it) {
    int idx = tid + it * 256;
    *(float4*)&sB2[idx * 4] = *(const float4*)(gW2 + (size_t)idx * 4);
  }
  __syncthreads();
  {
    const int rr = tid >> 2, q = tid & 3;
    float g0 = 0.f, g1 = 0.f, g2 = 0.f, g3 = 0.f;
    for (int k = 0; k < 256; ++k) {
      float a = sH[rr * 257 + k];
      float4 bv = *(const float4*)&sB2[k * 16 + q * 4];
      g0 = fmaf(a, bv.x, g0); g1 = fmaf(a, bv.y, g1);
      g2 = fmaf(a, bv.z, g2); g3 = fmaf(a, bv.w, g3);
    }
    sLog[rr * 16 + q * 4 + 0] = g0 + gb2[q * 4 + 0];
    sLog[rr * 16 + q * 4 + 1] = g1 + gb2[q * 4 + 1];
    sLog[rr * 16 + q * 4 + 2] = g2 + gb2[q * 4 + 2];
    sLog[rr * 16 + q * 4 + 3] = g3 + gb2[q * 4 + 3];
  }
  __syncthreads();
  float entc = 0.f;
  if (tid < 64) {
    const int row = row0 + tid;
    float gx[16], mx = -1e30f;
    #pragma unroll
    for (int e = 0; e < 16; ++e) { gx[e] = sLog[tid * 16 + e]; mx = fmaxf(mx, gx[e]); }
    float p[16], s = 0.f;
    #pragma unroll
    for (int e = 0; e < 16; ++e) { p[e] = expf(gx[e] - mx); s += p[e]; }
    const float inv = 1.f / s;
    #pragma unroll
    for (int e = 0; e < 16; ++e) {
      float pr = p[e] * inv;
      entc -= pr * logf(pr + 1e-9f);
    }
    int idxs[4]; float scs[4];
    unsigned used = 0;
    float wsum = 1e-9f;
    #pragma unroll
    for (int k = 0; k < 4; ++k) {
      int be = 0; float bv = -1.f;
      #pragma unroll
      for (int e = 0; e < 16; ++e) {
        float pr = p[e] * inv;
        if (!((used >> e) & 1u) && pr > bv) { bv = pr; be = e; }
      }
      used |= (1u << be);
      idxs[k] = be; scs[k] = bv;
      wsum += bv;
    }
    #pragma unroll
    for (int k = 0; k < 4; ++k) {
      topk_idx[row * 4 + k] = idxs[k];
      topk_w[row * 4 + k] = scs[k] / wsum;
      atomicAdd(&scnt[idxs[k]], 1);
    }
    #pragma unroll
    for (int off = 32; off > 0; off >>= 1) entc += __shfl_down(entc, off, 64);
  }
  __syncthreads();
  if (tid == 0) atomicAdd(ent_sum, entc);
  if (tid < 16 && scnt[tid] > 0) atomicAdd(&counts[tid], scnt[tid]);
}

// ---------------- offsets + aux loss ----------------
__global__ void k_aux(const int* __restrict__ counts, const float* __restrict__ ent_sum,
                      int* __restrict__ offsets, int* __restrict__ tbk,
                      float* __restrict__ aux_out) {
  if (threadIdx.x == 0) {
    int off = 0, t = 0;
    float load[16], mean = 0.f;
    for (int e = 0; e < 16; ++e) {
      offsets[e] = off; tbk[e] = t;
      int c = counts[e];
      off += c;
      t += (c + TM - 1) / TM;
      load[e] = (float)c / (32768.0f + 1e-9f);
      mean += load[e];
    }
    offsets[16] = off; tbk[16] = t;
    mean *= (1.f / 16.f);
    float var = 0.f;
    for (int e = 0; e < 16; ++e) { float d = load[e] - mean; var += d * d; }
    var *= (1.f / 15.f);
    *aux_out = var + ent_sum[0] * (1.0f / 32768.0f);
  }
}

// ------- scatter: block-aggregated (16 global atomics per block) -------
__global__ void k_scatter(const int* __restrict__ topk_idx, const float* __restrict__ topk_w,
                          const int* __restrict__ offsets, int* __restrict__ cursor,
                          int* __restrict__ slot_row, float* __restrict__ slot_w) {
  __shared__ int cnt[16];
  __shared__ int base[16];
  const int tid = threadIdx.x;
  if (tid < 16) cnt[tid] = 0;
  __syncthreads();
  const int row = blockIdx.x * 256 + tid;
  int e4[4]; float w4[4]; int lp[4];
  #pragma unroll
  for (int k = 0; k < 4; ++k) {
    e4[k] = topk_idx[row * 4 + k];
    w4[k] = topk_w[row * 4 + k];
    lp[k] = atomicAdd(&cnt[e4[k]], 1);
  }
  __syncthreads();
  if (tid < 16) base[tid] = atomicAdd(&cursor[tid], cnt[tid]);
  __syncthreads();
  #pragma unroll
  for (int k = 0; k < 4; ++k) {
    int s = offsets[e4[k]] + base[e4[k]] + lp[k];
    slot_row[s] = row;
    slot_w[s] = w4[k];
  }
}

// ------- fused expert: 3 MFMA layers + fW, 3-term split-bf16 -------
// 512 threads = 8 waves (2 M-groups x 4 N-groups); 2 blocks/CU -> 16 waves/CU.
__global__ __launch_bounds__(512, 4) void k_expert(
    const u16* __restrict__ inpHi, const u16* __restrict__ inpLo,
    const u16* __restrict__ eW1b, const float* __restrict__ eb1,
    const u16* __restrict__ eW2b, const float* __restrict__ eb2,
    const u16* __restrict__ eW3b, const float* __restrict__ eb3,
    const u16* __restrict__ fWb,
    const int* __restrict__ offsets, const int* __restrict__ counts,
    const int* __restrict__ tbk, const int* __restrict__ slot_row,
    const float* __restrict__ slot_w, float* __restrict__ out) {
  __shared__ __align__(16) u16 sHi[TM * LDP];
  __shared__ __align__(16) u16 sLo[TM * LDP];
  __shared__ int sRows[TM];
  __shared__ float sWv[TM];

  // XCD-chunked bijective remap: physical round-robin -> contiguous chunks/XCD
  const int bid = (blockIdx.x & 7) * CHUNK_E + (blockIdx.x >> 3);
  if (bid >= tbk[16]) return;
  int e = 0;
  #pragma unroll
  for (int i = 1; i < 16; ++i)
    if (bid >= tbk[i]) e = i;
  const int tile = bid - tbk[e];
  const int cnt = counts[e];
  const int s0 = offsets[e] + tile * TM;
  const int nr = min(TM, cnt - tile * TM);
  const int tid = threadIdx.x;
  const int l = tid & 63;
  const int w8 = tid >> 6;          // 0..7
  const int wm = w8 >> 2;           // 0..1  (M half)
  const int wn = w8 & 3;            // 0..3  (N quarter)
  const int g = l >> 4, r16 = l & 15;
  const int swz = (r16 & 7) << 3;   // XOR swizzle (16B granules) for A-row reads

  if (tid < TM) {
    sRows[tid] = (tid < nr) ? slot_row[s0 + tid] : slot_row[s0];
    sWv[tid] = (tid < nr) ? slot_w[s0 + tid] : 0.f;
  }
  __syncthreads();

  size_t rbase[2];
  #pragma unroll
  for (int mt = 0; mt < 2; ++mt)
    rbase[mt] = (size_t)sRows[(wm * 2 + mt) * 16 + r16] * INDP;

  f4v acc[2][4];
  #pragma unroll
  for (int i = 0; i < 2; ++i)
    #pragma unroll
    for (int j = 0; j < 4; ++j) acc[i][j] = (f4v){0.f, 0.f, 0.f, 0.f};

  // ---- layer 1: K=352, A direct from global planes ----
  const u16* W1 = eW1b + (size_t)e * 180224;
  for (int s = 0; s < 11; ++s) {
    s8v ah[2], al[2], bh[4], bl[4];
    #pragma unroll
    for (int mt = 0; mt < 2; ++mt) {
      size_t off = rbase[mt] + s * 32 + g * 8;
      ah[mt] = *(const s8v*)(inpHi + off);
      al[mt] = *(const s8v*)(inpLo + off);
    }
    #pragma unroll
    for (int j = 0; j < 4; ++j) {
      const u16* pb = W1 + (size_t)((s * 16 + wn * 4 + j) * 2) * 512 + l * 8;
      bh[j] = *(const s8v*)pb;
      bl[j] = *(const s8v*)(pb + 512);
    }
    #pragma unroll
    for (int mt = 0; mt < 2; ++mt)
      #pragma unroll
      for (int j = 0; j < 4; ++j) {
        acc[mt][j] = mfma16(ah[mt], bh[j], acc[mt][j]);
        acc[mt][j] = mfma16(al[mt], bh[j], acc[mt][j]);
        acc[mt][j] = mfma16(ah[mt], bl[j], acc[mt][j]);
      }
  }
  {
    const float* b1 = eb1 + e * HD;
    float bj[4];
    #pragma unroll
    for (int j = 0; j < 4; ++j) bj[j] = b1[wn * 64 + j * 16 + r16];
    #pragma unroll
    for (int mt = 0; mt < 2; ++mt)
      #pragma unroll
      for (int j = 0; j < 4; ++j)
        #pragma unroll
        for (int r = 0; r < 4; ++r) {
          int row = (wm * 2 + mt) * 16 + g * 4 + r;
          int col = wn * 64 + j * 16 + r16;
          float v = mishf(acc[mt][j][r] + bj[j]);
          u16 h = f2bf(v);
          int ec = col ^ ((row & 7) << 3);
          sHi[row * LDP + ec] = h;
          sLo[row * LDP + ec] = f2bf(v - bf2f(h));
        }
  }
  __syncthreads();

  // ---- layers 2 & 3: K=256, A from swizzled LDS planes ----
  #pragma unroll 1
  for (int L = 0; L < 2; ++L) {
    const u16* Wb = (L == 0 ? eW2b : eW3b) + (size_t)e * 131072;
    const float* bb = (L == 0 ? eb2 : eb3) + e * HD;
    f4v a2[2][4];
    #pragma unroll
    for (int i = 0; i < 2; ++i)
      #pragma unroll
      for (int j = 0; j < 4; ++j) a2[i][j] = (f4v){0.f, 0.f, 0.f, 0.f};
    #pragma unroll 2
    for (int s = 0; s < 8; ++s) {
      s8v ah[2], al[2], bh[4], bl[4];
      #pragma unroll
      for (int mt = 0; mt < 2; ++mt) {
        int row = (wm * 2 + mt) * 16 + r16;
        int ec = (s * 32 + g * 8) ^ swz;
        ah[mt] = *(const s8v*)&sHi[row * LDP + ec];
        al[mt] = *(const s8v*)&sLo[row * LDP + ec];
      }
      #pragma unroll
      for (int j = 0; j < 4; ++j) {
        const u16* pb = Wb + (size_t)((s * 16 + wn * 4 + j) * 2) * 512 + l * 8;
        bh[j] = *(const s8v*)pb;
        bl[j] = *(const s8v*)(pb + 512);
      }
      #pragma unroll
      for (int mt = 0; mt < 2; ++mt)
        #pragma unroll
        for (int j = 0; j < 4; ++j) {
          a2[mt][j] = mfma16(ah[mt], bh[j], a2[mt][j]);
          a2[mt][j] = mfma16(al[mt], bh[j], a2[mt][j]);
          a2[mt][j] = mfma16(ah[mt], bl[j], a2[mt][j]);
        }
    }
    __syncthreads();  // all reads of previous acts complete
    float bj[4];
    #pragma unroll
    for (int j = 0; j < 4; ++j) bj[j] = bb[wn * 64 + j * 16 + r16];
    #pragma unroll
    for (int mt = 0; mt < 2; ++mt)
      #pragma unroll
      for (int j = 0; j < 4; ++j)
        #pragma unroll
        for (int r = 0; r < 4; ++r) {
          int row = (wm * 2 + mt) * 16 + g * 4 + r;
          int col = wn * 64 + j * 16 + r16;
          float v = mishf(a2[mt][j][r] + bj[j]);
          u16 h = f2bf(v);
          int ec = col ^ ((row & 7) << 3);
          sHi[row * LDP + ec] = h;
          sLo[row * LDP + ec] = f2bf(v - bf2f(h));
        }
    __syncthreads();
  }

  // ---- final projection: K=256 -> N=64; wave (wm,wn): rows 2 tiles, cols wn*16.. ----
  f4v a3[2];
  #pragma unroll
  for (int i = 0; i < 2; ++i) a3[i] = (f4v){0.f, 0.f, 0.f, 0.f};
  #pragma unroll 2
  for (int s = 0; s < 8; ++s) {
    s8v ah[2], al[2];
    #pragma unroll
    for (int mt = 0; mt < 2; ++mt) {
      int row = (wm * 2 + mt) * 16 + r16;
      int ec = (s * 32 + g * 8) ^ swz;
      ah[mt] = *(const s8v*)&sHi[row * LDP + ec];
      al[mt] = *(const s8v*)&sLo[row * LDP + ec];
    }
    const u16* pb = fWb + (size_t)((s * 4 + wn) * 2) * 512 + l * 8;
    s8v bh = *(const s8v*)pb;
    s8v bl = *(const s8v*)(pb + 512);
    #pragma unroll
    for (int mt = 0; mt < 2; ++mt) {
      a3[mt] = mfma16(ah[mt], bh, a3[mt]);
      a3[mt] = mfma16(al[mt], bh, a3[mt]);
      a3[mt] = mfma16(ah[mt], bl, a3[mt]);
    }
  }
  #pragma unroll
  for (int mt = 0; mt < 2; ++mt)
    #pragma unroll
    for (int r = 0; r < 4; ++r) {
      int rl = (wm * 2 + mt) * 16 + g * 4 + r;
      if (rl < nr) {
        float v = a3[mt][r] * sWv[rl];
        atomicAdd(&out[(size_t)sRows[rl] * AD + wn * 16 + r16], v);
      }
    }
}

// ---------------- epilogue ----------------
__global__ void k_final(const float* __restrict__ x, const float* __restrict__ sigma,
                        const float* __restrict__ fb, float* __restrict__ out) {
  int i = blockIdx.x * 256 + threadIdx.x;
  if (i >= BN * AD) return;
  int row = i >> 6, c = i & 63;
  float sg = sigma[row];
  float sm = sg - 0.002f;
  float c_skip = 0.25f / (sm * sm + 0.25f);
  float c_out = sm * 0.5f * rsqrtf(sg * sg + 0.25f);
  float d = c_out * (out[i] + fb[c]) + c_skip * x[i];
  out[i] = fminf(fmaxf(d, -1.f), 1.f);
}

extern "C" void kernel_launch(void* const* d_in, const int* in_sizes, int n_in,
                              void* d_out, int out_size, void* d_ws, size_t ws_size,
                              hipStream_t stream) {
  const float* x     = (const float*)d_in[0];
  const float* sigma = (const float*)d_in[1];
  const float* state = (const float*)d_in[2];
  const float* tW1   = (const float*)d_in[3];
  const float* tb1   = (const float*)d_in[4];
  const float* tW2   = (const float*)d_in[5];
  const float* tb2   = (const float*)d_in[6];
  const float* gW1   = (const float*)d_in[7];
  const float* gb1   = (const float*)d_in[8];
  const float* gW2   = (const float*)d_in[9];
  const float* gb2   = (const float*)d_in[10];
  const float* eW1   = (const float*)d_in[11];
  const float* eb1   = (const float*)d_in[12];
  const float* eW2   = (const float*)d_in[13];
  const float* eb2   = (const float*)d_in[14];
  const float* eW3   = (const float*)d_in[15];
  const float* eb3   = (const float*)d_in[16];
  const float* fW    = (const float*)d_in[17];
  const float* fb    = (const float*)d_in[18];
  float* out = (float*)d_out;

  char* p = (char*)d_ws;
  auto alloc = [&](size_t bytes) { void* r = (void*)p; p += (bytes + 255) & ~(size_t)255; return r; };
  u16* inpHi  = (u16*)alloc((size_t)BN * INDP * 2);
  u16* inpLo  = (u16*)alloc((size_t)BN * INDP * 2);
  u16* inpMid = (u16*)alloc((size_t)BN * INDP * 2);
  u16* gW1b   = (u16*)alloc((size_t)11 * 16 * 3 * 512 * 2);
  u16* eW1b   = (u16*)alloc((size_t)16 * 180224 * 2);
  u16* eW2b   = (u16*)alloc((size_t)16 * 131072 * 2);
  u16* eW3b   = (u16*)alloc((size_t)16 * 131072 * 2);
  u16* fWb    = (u16*)alloc((size_t)32768 * 2);
  int*   topk_idx = (int*)alloc((size_t)BN * 4 * 4);
  float* topk_w   = (float*)alloc((size_t)BN * 4 * 4);
  int*   counts   = (int*)alloc(64);
  int*   cursor   = (int*)alloc(64);
  int*   offsets  = (int*)alloc(68);
  int*   tbk      = (int*)alloc(68);
  float* ent      = (float*)alloc(4);
  int*   slot_row = (int*)alloc((size_t)STOT * 4);
  float* slot_w   = (float*)alloc((size_t)STOT * 4);

  k_init<<<(BN * AD + 255) / 256, 256, 0, stream>>>(out, counts, cursor, ent);

  int tot;
  tot = 16 * 11 * 16 * 64;  // experts layer 1
  k_prep<<<(tot + 255) / 256, 256, 0, stream>>>(eW1, eW1b, 336, 11, 16, 256,
                                                (long)336 * 256, 180224, 2, tot);
  tot = 16 * 8 * 16 * 64;   // experts layers 2, 3
  k_prep<<<(tot + 255) / 256, 256, 0, stream>>>(eW2, eW2b, 256, 8, 16, 256,
                                                (long)256 * 256, 131072, 2, tot);
  k_prep<<<(tot + 255) / 256, 256, 0, stream>>>(eW3, eW3b, 256, 8, 16, 256,
                                                (long)256 * 256, 131072, 2, tot);
  tot = 11 * 16 * 64;       // gate layer 1 (3 planes)
  k_prep<<<(tot + 255) / 256, 256, 0, stream>>>(gW1, gW1b, 336, 11, 16, 256,
                                                0, 0, 3, tot);
  tot = 8 * 4 * 64;         // final projection
  k_prep<<<(tot + 255) / 256, 256, 0, stream>>>(fW, fWb, 256, 8, 4, 64,
                                                0, 0, 2, tot);

  k_time_inp<<<BN / 4, 256, 0, stream>>>(x, sigma, state, tW1, tb1, tW2, tb2,
                                         inpHi, inpLo, inpMid);
  k_gate<<<BN / TM, 256, 0, stream>>>(inpHi, inpLo, inpMid, gW1b, gb1, gW2, gb2,
                                      topk_idx, topk_w, counts, ent);
  k_aux<<<1, 64, 0, stream>>>(counts, ent, offsets, tbk, out + (size_t)BN * AD);
  k_scatter<<<BN / 256, 256, 0, stream>>>(topk_idx, topk_w, offsets, cursor, slot_row, slot_w);
  k_expert<<<GRID_E, 512, 0, stream>>>(inpHi, inpLo, eW1b, eb1, eW2b, eb2,
                                       eW3b, eb3, fWb, offsets, counts, tbk,
                                       slot_row, slot_w, out);
  k_final<<<(BN * AD + 255) / 256, 256, 0, stream>>>(x, sigma, fb, out);
}

// Round 6
// 467.114 us; speedup vs baseline: 6.5251x; 1.1162x over previous
//
#include <hip/hip_runtime.h>
#include <math.h>

#define BN 32768
#define INDP 352      // padded input width (336 -> 352, zero-filled)
#define HD 256
#define AD 64
#define EN 16
#define TME 32        // expert/gate tile rows
#define STOT (BN * 4)
#define GRID_E 4112   // 8 * 514 >= max tiles (4111)
#define CHUNK_E 514

typedef __attribute__((ext_vector_type(8))) short s8v;
typedef __attribute__((ext_vector_type(4))) float f4v;
typedef unsigned short u16;

__device__ __forceinline__ u16 f2bf(float x) {
  unsigned u = __float_as_uint(x);
  return (u16)((u + 0x7fffu + ((u >> 16) & 1u)) >> 16);
}
__device__ __forceinline__ float bf2f(u16 h) { return __uint_as_float(((unsigned)h) << 16); }
__device__ __forceinline__ float rcpf(float a) { float r; asm("v_rcp_f32 %0, %1" : "=v"(r) : "v"(a)); return r; }
// mish(x) = x*tanh(softplus(x)) = x*(u^2+2u)/(u^2+2u+2), u=e^x (exact algebraic rewrite)
__device__ __forceinline__ float mishf(float x) {
  float xc = fminf(x, 30.f);
  float u = __expf(xc);
  float w = fmaf(u, u, u + u);
  return x * w * rcpf(w + 2.f);
}
__device__ __forceinline__ f4v mfma16(s8v a, s8v b, f4v c) {
  return __builtin_amdgcn_mfma_f32_16x16x32_bf16(a, b, c, 0, 0, 0);
}
__device__ __forceinline__ void pack8(const u16* q, u16* d) {
  uint4 u;
  u.x = q[0] | ((unsigned)q[1] << 16); u.y = q[2] | ((unsigned)q[3] << 16);
  u.z = q[4] | ((unsigned)q[5] << 16); u.w = q[6] | ((unsigned)q[7] << 16);
  *(uint4*)d = u;
}

// ---------------- init ----------------
__global__ void k_init(float* __restrict__ out, int* __restrict__ counts,
                       int* __restrict__ cursor, float* __restrict__ ent) {
  int i = blockIdx.x * 256 + threadIdx.x;
  if (i < BN * AD) out[i] = 0.f;
  if (i < 16) { counts[i] = 0; cursor[i] = 0; }
  if (i == 16) *ent = 0.f;
}

// ------- weight prep: fp32 [K][N] -> fragment-ordered split-bf16 planes -------
// dst (u16 units): [s][nt][plane 0..NP-1][lane 0..63][8]; elem i of lane l:
//   k = s*32 + 8*(l>>4) + i, n = nt*16 + (l&15)
__global__ void k_prep(const float* __restrict__ src, u16* __restrict__ dst,
                       int Ksrc, int Spad, int NT, int N,
                       long sStride, long dStride, int NP, int total) {
  int idx = blockIdx.x * 256 + threadIdx.x;
  if (idx >= total) return;
  int l = idx & 63;
  int t = idx >> 6;
  int nt = t % NT; t /= NT;
  int s = t % Spad; t /= Spad;
  int m = t;
  const float* sp = src + (size_t)m * sStride;
  int n = nt * 16 + (l & 15);
  int kb = s * 32 + (l >> 4) * 8;
  u16 q0[8], q1[8], q2[8];
  #pragma unroll
  for (int i = 0; i < 8; ++i) {
    int k = kb + i;
    float v = (k < Ksrc) ? sp[(size_t)k * N + n] : 0.f;
    u16 a = f2bf(v); float r1 = v - bf2f(a);
    u16 b = f2bf(r1); float r2 = r1 - bf2f(b);
    q0[i] = a; q1[i] = b; q2[i] = f2bf(r2);
  }
  u16* d = dst + (size_t)m * dStride + (size_t)((s * NT + nt) * NP) * 512 + l * 8;
  pack8(q0, d);
  pack8(q1, d + 512);
  if (NP == 3) pack8(q2, d + 1024);
}

// ------- time embedding + input assembly (3 split-bf16 planes) -------
__global__ void k_time_inp(const float* __restrict__ x, const float* __restrict__ sigma,
                           const float* __restrict__ state,
                           const float* __restrict__ tW1, const float* __restrict__ tb1,
                           const float* __restrict__ tW2, const float* __restrict__ tb2,
                           u16* __restrict__ p0, u16* __restrict__ p1, u16* __restrict__ p2) {
  const int wv = threadIdx.x >> 6;
  const int lane = threadIdx.x & 63;
  const int row = blockIdx.x * 4 + wv;
  const float sg = sigma[row];
  const float rt = 250.0f * logf(sg + 1e-44f);
  float pe = 0.f;
  if (lane < 16) {
    int j = lane & 7;
    float f = expf(-1.3157629102823121f * (float)j);  // -ln(10000)/7 * j
    float ang = rt * f;
    pe = (lane < 8) ? sinf(ang) : cosf(ang);
  }
  float h1;
  {
    float acc = 0.f;
    int j = lane & 31;
    #pragma unroll
    for (int i = 0; i < 16; ++i) {
      float p = __shfl(pe, i, 64);
      acc = fmaf(p, tW1[i * 32 + j], acc);
    }
    acc += tb1[j];
    float sp = log1pf(expf(acc));
    h1 = acc * tanhf(sp);
  }
  float t2;
  {
    float acc = 0.f;
    int j = lane & 15;
    #pragma unroll
    for (int i = 0; i < 32; ++i) {
      float h = __shfl(h1, i, 64);
      acc = fmaf(h, tW2[i * 16 + j], acc);
    }
    t2 = acc + tb2[j];
  }
  const float c_in = rsqrtf(sg * sg + 0.25f);
  u16* r0 = p0 + (size_t)row * INDP;
  u16* r1 = p1 + (size_t)row * INDP;
  u16* r2 = p2 + (size_t)row * INDP;
  auto wsplit = [&](int c, float v) {
    u16 a = f2bf(v); float ra = v - bf2f(a);
    u16 b = f2bf(ra); float rb = ra - bf2f(b);
    r0[c] = a; r1[c] = b; r2[c] = f2bf(rb);
  };
  wsplit(lane, c_in * x[row * 64 + lane]);
  if (lane < 16) wsplit(64 + lane, t2);
  #pragma unroll
  for (int r = 0; r < 4; ++r)
    wsplit(80 + r * 64 + lane, state[(size_t)row * 256 + r * 64 + lane]);
  if (lane < 16) { r0[336 + lane] = 0; r1[336 + lane] = 0; r2[336 + lane] = 0; }
}

// ------- gate: TM=32, all-MFMA (6-term L1, 6-term L2), 3 H-planes in LDS -------
__global__ __launch_bounds__(256, 3) void k_gate(
    const u16* __restrict__ p0, const u16* __restrict__ p1, const u16* __restrict__ p2,
    const u16* __restrict__ gW1b, const float* __restrict__ gb1,
    const u16* __restrict__ gW2b, const float* __restrict__ gb2,
    int* __restrict__ topk_idx, float* __restrict__ topk_w,
    int* __restrict__ counts, float* __restrict__ ent_sum) {
  __shared__ __align__(16) u16 sH0[TME * 256];
  __shared__ __align__(16) u16 sH1[TME * 256];
  __shared__ __align__(16) u16 sH2[TME * 256];
  __shared__ float sLog[TME * 16];
  __shared__ int scnt[16];
  const int tid = threadIdx.x;
  const int l = tid & 63, wn = tid >> 6;
  const int g = l >> 4, r16 = l & 15;
  const int row0 = blockIdx.x * TME;
  const int swz = (r16 & 7) << 3;
  if (tid < 16) scnt[tid] = 0;

  f4v acc[2][4];
  #pragma unroll
  for (int i = 0; i < 2; ++i)
    #pragma unroll
    for (int j = 0; j < 4; ++j) acc[i][j] = (f4v){0.f, 0.f, 0.f, 0.f};

  #pragma unroll 2
  for (int s = 0; s < 11; ++s) {
    s8v a0[2], a1[2], a2[2], b0[4], b1[4], b2[4];
    #pragma unroll
    for (int mt = 0; mt < 2; ++mt) {
      size_t off = (size_t)(row0 + mt * 16 + r16) * INDP + s * 32 + g * 8;
      a0[mt] = *(const s8v*)(p0 + off);
      a1[mt] = *(const s8v*)(p1 + off);
      a2[mt] = *(const s8v*)(p2 + off);
    }
    #pragma unroll
    for (int j = 0; j < 4; ++j) {
      const u16* pb = gW1b + (size_t)((s * 16 + wn * 4 + j) * 3) * 512 + l * 8;
      b0[j] = *(const s8v*)pb;
      b1[j] = *(const s8v*)(pb + 512);
      b2[j] = *(const s8v*)(pb + 1024);
    }
    #pragma unroll
    for (int mt = 0; mt < 2; ++mt)
      #pragma unroll
      for (int j = 0; j < 4; ++j) {
        acc[mt][j] = mfma16(a0[mt], b0[j], acc[mt][j]);
        acc[mt][j] = mfma16(a0[mt], b1[j], acc[mt][j]);
        acc[mt][j] = mfma16(a1[mt], b0[j], acc[mt][j]);
        acc[mt][j] = mfma16(a1[mt], b1[j], acc[mt][j]);
        acc[mt][j] = mfma16(a0[mt], b2[j], acc[mt][j]);
        acc[mt][j] = mfma16(a2[mt], b0[j], acc[mt][j]);
      }
  }
  // relu + 3-way split into LDS planes (swizzled)
  #pragma unroll
  for (int mt = 0; mt < 2; ++mt)
    #pragma unroll
    for (int j = 0; j < 4; ++j) {
      float bj = gb1[wn * 64 + j * 16 + r16];
      #pragma unroll
      for (int r = 0; r < 4; ++r) {
        int row = mt * 16 + g * 4 + r;
        int col = wn * 64 + j * 16 + r16;
        float v = fmaxf(acc[mt][j][r] + bj, 0.f);
        u16 h0 = f2bf(v); float ra = v - bf2f(h0);
        u16 h1 = f2bf(ra); float rb = ra - bf2f(h1);
        int ec = col ^ ((row & 7) << 3);
        sH0[row * 256 + ec] = h0;
        sH1[row * 256 + ec] = h1;
        sH2[row * 256 + ec] = f2bf(rb);
      }
    }
  __syncthreads();

  // L2: 256 -> 16, 6-term, all waves compute redundantly (B frags from global)
  f4v l2[2];
  l2[0] = (f4v){0.f, 0.f, 0.f, 0.f};
  l2[1] = (f4v){0.f, 0.f, 0.f, 0.f};
  #pragma unroll
  for (int s = 0; s < 8; ++s) {
    const u16* pb = gW2b + (size_t)(s * 3) * 512 + l * 8;
    s8v b0 = *(const s8v*)pb;
    s8v b1 = *(const s8v*)(pb + 512);
    s8v b2 = *(const s8v*)(pb + 1024);
    #pragma unroll
    for (int mt = 0; mt < 2; ++mt) {
      int row = mt * 16 + r16;
      int ec = (s * 32 + g * 8) ^ swz;
      s8v a0 = *(const s8v*)&sH0[row * 256 + ec];
      s8v a1 = *(const s8v*)&sH1[row * 256 + ec];
      s8v a2 = *(const s8v*)&sH2[row * 256 + ec];
      l2[mt] = mfma16(a0, b0, l2[mt]);
      l2[mt] = mfma16(a0, b1, l2[mt]);
      l2[mt] = mfma16(a1, b0, l2[mt]);
      l2[mt] = mfma16(a1, b1, l2[mt]);
      l2[mt] = mfma16(a0, b2, l2[mt]);
      l2[mt] = mfma16(a2, b0, l2[mt]);
    }
  }
  if (wn == 0) {
    #pragma unroll
    for (int mt = 0; mt < 2; ++mt)
      #pragma unroll
      for (int r = 0; r < 4; ++r)
        sLog[(mt * 16 + g * 4 + r) * 16 + r16] = l2[mt][r] + gb2[r16];
  }
  __syncthreads();

  float entc = 0.f;
  if (tid < TME) {
    const int row = row0 + tid;
    float gx[16], mx = -1e30f;
    #pragma unroll
    for (int e = 0; e < 16; ++e) { gx[e] = sLog[tid * 16 + e]; mx = fmaxf(mx, gx[e]); }
    float p[16], s = 0.f;
    #pragma unroll
    for (int e = 0; e < 16; ++e) { p[e] = expf(gx[e] - mx); s += p[e]; }
    const float inv = 1.f / s;
    #pragma unroll
    for (int e = 0; e < 16; ++e) {
      float pr = p[e] * inv;
      entc -= pr * logf(pr + 1e-9f);
    }
    int idxs[4]; float scs[4];
    unsigned used = 0;
    float wsum = 1e-9f;
    #pragma unroll
    for (int k = 0; k < 4; ++k) {
      int be = 0; float bv = -1.f;
      #pragma unroll
      for (int e = 0; e < 16; ++e) {
        float pr = p[e] * inv;
        if (!((used >> e) & 1u) && pr > bv) { bv = pr; be = e; }
      }
      used |= (1u << be);
      idxs[k] = be; scs[k] = bv;
      wsum += bv;
    }
    #pragma unroll
    for (int k = 0; k < 4; ++k) {
      topk_idx[row * 4 + k] = idxs[k];
      topk_w[row * 4 + k] = scs[k] / wsum;
      atomicAdd(&scnt[idxs[k]], 1);
    }
  }
  if (tid < 64) {
    #pragma unroll
    for (int off = 32; off > 0; off >>= 1) entc += __shfl_down(entc, off, 64);
  }
  if (tid == 0) atomicAdd(ent_sum, entc);
  __syncthreads();
  if (tid < 16 && scnt[tid] > 0) atomicAdd(&counts[tid], scnt[tid]);
}

// ---------------- offsets + aux loss ----------------
__global__ void k_aux(const int* __restrict__ counts, const float* __restrict__ ent_sum,
                      int* __restrict__ offsets, int* __restrict__ tbk,
                      float* __restrict__ aux_out) {
  if (threadIdx.x == 0) {
    int off = 0, t = 0;
    float load[16], mean = 0.f;
    for (int e = 0; e < 16; ++e) {
      offsets[e] = off; tbk[e] = t;
      int c = counts[e];
      off += c;
      t += (c + TME - 1) / TME;
      load[e] = (float)c / (32768.0f + 1e-9f);
      mean += load[e];
    }
    offsets[16] = off; tbk[16] = t;
    mean *= (1.f / 16.f);
    float var = 0.f;
    for (int e = 0; e < 16; ++e) { float d = load[e] - mean; var += d * d; }
    var *= (1.f / 15.f);
    *aux_out = var + ent_sum[0] * (1.0f / 32768.0f);
  }
}

// ------- scatter: block-aggregated (16 global atomics per block) -------
__global__ void k_scatter(const int* __restrict__ topk_idx, const float* __restrict__ topk_w,
                          const int* __restrict__ offsets, int* __restrict__ cursor,
                          int* __restrict__ slot_row, float* __restrict__ slot_w) {
  __shared__ int cnt[16];
  __shared__ int base[16];
  const int tid = threadIdx.x;
  if (tid < 16) cnt[tid] = 0;
  __syncthreads();
  const int row = blockIdx.x * 256 + tid;
  int e4[4]; float w4[4]; int lp[4];
  #pragma unroll
  for (int k = 0; k < 4; ++k) {
    e4[k] = topk_idx[row * 4 + k];
    w4[k] = topk_w[row * 4 + k];
    lp[k] = atomicAdd(&cnt[e4[k]], 1);
  }
  __syncthreads();
  if (tid < 16) base[tid] = atomicAdd(&cursor[tid], cnt[tid]);
  __syncthreads();
  #pragma unroll
  for (int k = 0; k < 4; ++k) {
    int s = offsets[e4[k]] + base[e4[k]] + lp[k];
    slot_row[s] = row;
    slot_w[s] = w4[k];
  }
}

// ------- fused expert: TM=32, 256 thr / 4 waves, 4 blocks/CU -------
__global__ __launch_bounds__(256, 4) void k_expert(
    const u16* __restrict__ inpHi, const u16* __restrict__ inpLo,
    const u16* __restrict__ eW1b, const float* __restrict__ eb1,
    const u16* __restrict__ eW2b, const float* __restrict__ eb2,
    const u16* __restrict__ eW3b, const float* __restrict__ eb3,
    const u16* __restrict__ fWb,
    const int* __restrict__ offsets, const int* __restrict__ counts,
    const int* __restrict__ tbk, const int* __restrict__ slot_row,
    const float* __restrict__ slot_w, float* __restrict__ out) {
  __shared__ __align__(16) u16 sHi[TME * 256];
  __shared__ __align__(16) u16 sLo[TME * 256];
  __shared__ int sRows[TME];
  __shared__ float sWv[TME];

  // XCD-chunked bijective remap
  const int bid = (blockIdx.x & 7) * CHUNK_E + (blockIdx.x >> 3);
  if (bid >= tbk[16]) return;
  int e = 0;
  #pragma unroll
  for (int i = 1; i < 16; ++i)
    if (bid >= tbk[i]) e = i;
  const int tile = bid - tbk[e];
  const int cnt = counts[e];
  const int s0 = offsets[e] + tile * TME;
  const int nr = min(TME, cnt - tile * TME);
  const int tid = threadIdx.x;
  const int l = tid & 63;
  const int wn = tid >> 6;          // 0..3 (N quarter)
  const int g = l >> 4, r16 = l & 15;
  const int swz = (r16 & 7) << 3;

  if (tid < TME) {
    sRows[tid] = (tid < nr) ? slot_row[s0 + tid] : slot_row[s0];
    sWv[tid] = (tid < nr) ? slot_w[s0 + tid] : 0.f;
  }
  __syncthreads();

  size_t rbase[2];
  #pragma unroll
  for (int mt = 0; mt < 2; ++mt)
    rbase[mt] = (size_t)sRows[mt * 16 + r16] * INDP;

  f4v acc[2][4];
  #pragma unroll
  for (int i = 0; i < 2; ++i)
    #pragma unroll
    for (int j = 0; j < 4; ++j) acc[i][j] = (f4v){0.f, 0.f, 0.f, 0.f};

  // ---- layer 1: K=352, A direct from global planes ----
  const u16* W1 = eW1b + (size_t)e * 180224;
  #pragma unroll 2
  for (int s = 0; s < 11; ++s) {
    s8v ah[2], al[2], bh[4], bl[4];
    #pragma unroll
    for (int mt = 0; mt < 2; ++mt) {
      size_t off = rbase[mt] + s * 32 + g * 8;
      ah[mt] = *(const s8v*)(inpHi + off);
      al[mt] = *(const s8v*)(inpLo + off);
    }
    #pragma unroll
    for (int j = 0; j < 4; ++j) {
      const u16* pb = W1 + (size_t)((s * 16 + wn * 4 + j) * 2) * 512 + l * 8;
      bh[j] = *(const s8v*)pb;
      bl[j] = *(const s8v*)(pb + 512);
    }
    #pragma unroll
    for (int mt = 0; mt < 2; ++mt)
      #pragma unroll
      for (int j = 0; j < 4; ++j) {
        acc[mt][j] = mfma16(ah[mt], bh[j], acc[mt][j]);
        acc[mt][j] = mfma16(al[mt], bh[j], acc[mt][j]);
        acc[mt][j] = mfma16(ah[mt], bl[j], acc[mt][j]);
      }
  }
  {
    const float* b1 = eb1 + e * HD;
    #pragma unroll
    for (int mt = 0; mt < 2; ++mt)
      #pragma unroll
      for (int j = 0; j < 4; ++j) {
        float bj = b1[wn * 64 + j * 16 + r16];
        #pragma unroll
        for (int r = 0; r < 4; ++r) {
          int row = mt * 16 + g * 4 + r;
          int col = wn * 64 + j * 16 + r16;
          float v = mishf(acc[mt][j][r] + bj);
          u16 h = f2bf(v);
          int ec = col ^ ((row & 7) << 3);
          sHi[row * 256 + ec] = h;
          sLo[row * 256 + ec] = f2bf(v - bf2f(h));
        }
      }
  }
  __syncthreads();

  // ---- layers 2 & 3: K=256, A from swizzled LDS planes ----
  #pragma unroll 1
  for (int L = 0; L < 2; ++L) {
    const u16* Wb = (L == 0 ? eW2b : eW3b) + (size_t)e * 131072;
    const float* bb = (L == 0 ? eb2 : eb3) + e * HD;
    f4v a2[2][4];
    #pragma unroll
    for (int i = 0; i < 2; ++i)
      #pragma unroll
      for (int j = 0; j < 4; ++j) a2[i][j] = (f4v){0.f, 0.f, 0.f, 0.f};
    #pragma unroll 2
    for (int s = 0; s < 8; ++s) {
      s8v ah[2], al[2], bh[4], bl[4];
      #pragma unroll
      for (int mt = 0; mt < 2; ++mt) {
        int row = mt * 16 + r16;
        int ec = (s * 32 + g * 8) ^ swz;
        ah[mt] = *(const s8v*)&sHi[row * 256 + ec];
        al[mt] = *(const s8v*)&sLo[row * 256 + ec];
      }
      #pragma unroll
      for (int j = 0; j < 4; ++j) {
        const u16* pb = Wb + (size_t)((s * 16 + wn * 4 + j) * 2) * 512 + l * 8;
        bh[j] = *(const s8v*)pb;
        bl[j] = *(const s8v*)(pb + 512);
      }
      #pragma unroll
      for (int mt = 0; mt < 2; ++mt)
        #pragma unroll
        for (int j = 0; j < 4; ++j) {
          a2[mt][j] = mfma16(ah[mt], bh[j], a2[mt][j]);
          a2[mt][j] = mfma16(al[mt], bh[j], a2[mt][j]);
          a2[mt][j] = mfma16(ah[mt], bl[j], a2[mt][j]);
        }
    }
    __syncthreads();  // all reads of previous acts complete
    #pragma unroll
    for (int mt = 0; mt < 2; ++mt)
      #pragma unroll
      for (int j = 0; j < 4; ++j) {
        float bj = bb[wn * 64 + j * 16 + r16];
        #pragma unroll
        for (int r = 0; r < 4; ++r) {
          int row = mt * 16 + g * 4 + r;
          int col = wn * 64 + j * 16 + r16;
          float v = mishf(a2[mt][j][r] + bj);
          u16 h = f2bf(v);
          int ec = col ^ ((row & 7) << 3);
          sHi[row * 256 + ec] = h;
          sLo[row * 256 + ec] = f2bf(v - bf2f(h));
        }
      }
    __syncthreads();
  }

  // ---- final projection: K=256 -> N=64; wave wn owns cols wn*16..+16 ----
  f4v a3[2];
  a3[0] = (f4v){0.f, 0.f, 0.f, 0.f};
  a3[1] = (f4v){0.f, 0.f, 0.f, 0.f};
  #pragma unroll 2
  for (int s = 0; s < 8; ++s) {
    s8v ah[2], al[2];
    #pragma unroll
    for (int mt = 0; mt < 2; ++mt) {
      int row = mt * 16 + r16;
      int ec = (s * 32 + g * 8) ^ swz;
      ah[mt] = *(const s8v*)&sHi[row * 256 + ec];
      al[mt] = *(const s8v*)&sLo[row * 256 + ec];
    }
    const u16* pb = fWb + (size_t)((s * 4 + wn) * 2) * 512 + l * 8;
    s8v bh = *(const s8v*)pb;
    s8v bl = *(const s8v*)(pb + 512);
    #pragma unroll
    for (int mt = 0; mt < 2; ++mt) {
      a3[mt] = mfma16(ah[mt], bh, a3[mt]);
      a3[mt] = mfma16(al[mt], bh, a3[mt]);
      a3[mt] = mfma16(ah[mt], bl, a3[mt]);
    }
  }
  #pragma unroll
  for (int mt = 0; mt < 2; ++mt)
    #pragma unroll
    for (int r = 0; r < 4; ++r) {
      int rl = mt * 16 + g * 4 + r;
      if (rl < nr) {
        float v = a3[mt][r] * sWv[rl];
        atomicAdd(&out[(size_t)sRows[rl] * AD + wn * 16 + r16], v);
      }
    }
}

// ---------------- epilogue ----------------
__global__ void k_final(const float* __restrict__ x, const float* __restrict__ sigma,
                        const float* __restrict__ fb, float* __restrict__ out) {
  int i = blockIdx.x * 256 + threadIdx.x;
  if (i >= BN * AD) return;
  int row = i >> 6, c = i & 63;
  float sg = sigma[row];
  float sm = sg - 0.002f;
  float c_skip = 0.25f / (sm * sm + 0.25f);
  float c_out = sm * 0.5f * rsqrtf(sg * sg + 0.25f);
  float d = c_out * (out[i] + fb[c]) + c_skip * x[i];
  out[i] = fminf(fmaxf(d, -1.f), 1.f);
}

extern "C" void kernel_launch(void* const* d_in, const int* in_sizes, int n_in,
                              void* d_out, int out_size, void* d_ws, size_t ws_size,
                              hipStream_t stream) {
  const float* x     = (const float*)d_in[0];
  const float* sigma = (const float*)d_in[1];
  const float* state = (const float*)d_in[2];
  const float* tW1   = (const float*)d_in[3];
  const float* tb1   = (const float*)d_in[4];
  const float* tW2   = (const float*)d_in[5];
  const float* tb2   = (const float*)d_in[6];
  const float* gW1   = (const float*)d_in[7];
  const float* gb1   = (const float*)d_in[8];
  const float* gW2   = (const float*)d_in[9];
  const float* gb2   = (const float*)d_in[10];
  const float* eW1   = (const float*)d_in[11];
  const float* eb1   = (const float*)d_in[12];
  const float* eW2   = (const float*)d_in[13];
  const float* eb2   = (const float*)d_in[14];
  const float* eW3   = (const float*)d_in[15];
  const float* eb3   = (const float*)d_in[16];
  const float* fW    = (const float*)d_in[17];
  const float* fb    = (const float*)d_in[18];
  float* out = (float*)d_out;

  char* p = (char*)d_ws;
  auto alloc = [&](size_t bytes) { void* r = (void*)p; p += (bytes + 255) & ~(size_t)255; return r; };
  u16* inpHi  = (u16*)alloc((size_t)BN * INDP * 2);
  u16* inpLo  = (u16*)alloc((size_t)BN * INDP * 2);
  u16* inpMid = (u16*)alloc((size_t)BN * INDP * 2);
  u16* gW1b   = (u16*)alloc((size_t)11 * 16 * 3 * 512 * 2);
  u16* gW2b   = (u16*)alloc((size_t)8 * 3 * 512 * 2);
  u16* eW1b   = (u16*)alloc((size_t)16 * 180224 * 2);
  u16* eW2b   = (u16*)alloc((size_t)16 * 131072 * 2);
  u16* eW3b   = (u16*)alloc((size_t)16 * 131072 * 2);
  u16* fWb    = (u16*)alloc((size_t)32768 * 2);
  int*   topk_idx = (int*)alloc((size_t)BN * 4 * 4);
  float* topk_w   = (float*)alloc((size_t)BN * 4 * 4);
  int*   counts   = (int*)alloc(64);
  int*   cursor   = (int*)alloc(64);
  int*   offsets  = (int*)alloc(68);
  int*   tbk      = (int*)alloc(68);
  float* ent      = (float*)alloc(4);
  int*   slot_row = (int*)alloc((size_t)STOT * 4);
  float* slot_w   = (float*)alloc((size_t)STOT * 4);

  k_init<<<(BN * AD + 255) / 256, 256, 0, stream>>>(out, counts, cursor, ent);

  int tot;
  tot = 16 * 11 * 16 * 64;  // experts layer 1
  k_prep<<<(tot + 255) / 256, 256, 0, stream>>>(eW1, eW1b, 336, 11, 16, 256,
                                                (long)336 * 256, 180224, 2, tot);
  tot = 16 * 8 * 16 * 64;   // experts layers 2, 3
  k_prep<<<(tot + 255) / 256, 256, 0, stream>>>(eW2, eW2b, 256, 8, 16, 256,
                                                (long)256 * 256, 131072, 2, tot);
  k_prep<<<(tot + 255) / 256, 256, 0, stream>>>(eW3, eW3b, 256, 8, 16, 256,
                                                (long)256 * 256, 131072, 2, tot);
  tot = 11 * 16 * 64;       // gate layer 1 (3 planes)
  k_prep<<<(tot + 255) / 256, 256, 0, stream>>>(gW1, gW1b, 336, 11, 16, 256,
                                                0, 0, 3, tot);
  tot = 8 * 1 * 64;         // gate layer 2 (3 planes, N=16)
  k_prep<<<(tot + 255) / 256, 256, 0, stream>>>(gW2, gW2b, 256, 8, 1, 16,
                                                0, 0, 3, tot);
  tot = 8 * 4 * 64;         // final projection
  k_prep<<<(tot + 255) / 256, 256, 0, stream>>>(fW, fWb, 256, 8, 4, 64,
                                                0, 0, 2, tot);

  k_time_inp<<<BN / 4, 256, 0, stream>>>(x, sigma, state, tW1, tb1, tW2, tb2,
                                         inpHi, inpLo, inpMid);
  k_gate<<<BN / TME, 256, 0, stream>>>(inpHi, inpLo, inpMid, gW1b, gb1, gW2b, gb2,
                                       topk_idx, topk_w, counts, ent);
  k_aux<<<1, 64, 0, stream>>>(counts, ent, offsets, tbk, out + (size_t)BN * AD);
  k_scatter<<<BN / 256, 256, 0, stream>>>(topk_idx, topk_w, offsets, cursor, slot_row, slot_w);
  k_expert<<<GRID_E, 256, 0, stream>>>(inpHi, inpLo, eW1b, eb1, eW2b, eb2,
                                       eW3b, eb3, fWb, offsets, counts, tbk,
                                       slot_row, slot_w, out);
  k_final<<<(BN * AD + 255) / 256, 256, 0, stream>>>(x, sigma, fb, out);
}